// Round 4
// baseline (291.014 us; speedup 1.0000x reference)
//
#include <hip/hip_runtime.h>
#include <stdint.h>

typedef unsigned short u16;
typedef short bf16x8 __attribute__((ext_vector_type(8)));   // 8 bf16 in 4 VGPRs
typedef float f32x4 __attribute__((ext_vector_type(4)));

typedef void as1_void __attribute__((address_space(1)));
typedef void as3_void __attribute__((address_space(3)));

__device__ inline u16 f32_to_bf16(float f) {
    uint32_t u = __builtin_bit_cast(uint32_t, f);
    u += 0x7fffu + ((u >> 16) & 1u);   // RNE (finite values only)
    return (u16)(u >> 16);
}

__device__ inline void gld_lds16(const void* g, void* l) {
    // async global->LDS, 16B/lane; HW dest = wave-uniform base + lane*16
    __builtin_amdgcn_global_load_lds((as1_void*)g, (as3_void*)l, 16, 0, 0);
}

// LDS tile layout (all GEMMs): R rows x 64 cols bf16, stored as R*8 chunks of
// 16B. Global (row, colchunk j) lives at chunk slot row*8 + (j ^ (row&7)).
// The XOR swizzle spreads same-column frag reads across all 32 banks (2-way max,
// free per m136) while keeping each staging issue 64 lane-contiguous slots.
// (Measured SQ_LDS_BANK_CONFLICT = 0 with this scheme.)

// ---------------- merged prep kernel ----------------
// blocks [0,4096):     Ccat[o][k] = [Cr | -Ci]  row-major [1024][4096] bf16
// blocks [4096,8192):  Bcat[c][colOff+r] = bf16(src[r][c]) (32x32 LDS transpose)
// blocks [8192,10240): Cwbf[o][h] = bf16(Cr*wr - Ci*wi), w recomputed inline

__global__ void prep_kernel(const float* __restrict__ Cr, const float* __restrict__ Ci,
                            const float* __restrict__ Br, const float* __restrict__ Bi,
                            const float* __restrict__ v_log, const float* __restrict__ th_log,
                            u16* __restrict__ Ccat, u16* __restrict__ Bcat,
                            u16* __restrict__ Cwbf)
{
    __shared__ float t[32][33];
    const int b = blockIdx.x, tid = threadIdx.x;

    if (b < 4096) {
        // ---- pack Ccat = [Cr | -Ci] ----
        int i = b * 256 + tid;
        int e = i * 4;
        int o = e >> 12;
        int k = e & 4095;
        float4 f; float s;
        if (k < 2048) { f = *(const float4*)(Cr + (size_t)o * 2048 + k);          s =  1.f; }
        else          { f = *(const float4*)(Ci + (size_t)o * 2048 + (k - 2048)); s = -1.f; }
        ushort4 u;
        u.x = f32_to_bf16(s * f.x); u.y = f32_to_bf16(s * f.y);
        u.z = f32_to_bf16(s * f.z); u.w = f32_to_bf16(s * f.w);
        ((ushort4*)Ccat)[i] = u;
    } else if (b < 8192) {
        // ---- transpose-cast Bcat = [Br^T | Bi^T] ----
        int b2 = b - 4096;
        const float* src = (b2 & 2048) ? Bi : Br;
        int colOff = (b2 & 2048) ? 2048 : 0;
        int c0 = (b2 & 31) * 32, r0 = ((b2 >> 5) & 63) * 32;
        int tx = tid & 31, ty = tid >> 5;   // 32 x 8
#pragma unroll
        for (int j = 0; j < 4; j++)
            t[ty + j * 8][tx] = src[(size_t)(r0 + ty + j * 8) * 1024 + c0 + tx];
        __syncthreads();
#pragma unroll
        for (int j = 0; j < 4; j++)
            Bcat[(size_t)(c0 + ty + j * 8) * 4096 + colOff + r0 + tx] =
                f32_to_bf16(t[tx][ty + j * 8]);
    } else {
        // ---- Cwbf = bf16(Cr*wr - Ci*wi); w recomputed per element (cheap trans) ----
        int j = (b - 8192) * 256 + tid;
        int e = j * 4;
        int o = e >> 11;
        int h = e & 2047;
        float4 cr = *(const float4*)(Cr + (size_t)o * 2048 + h);
        float4 ci = *(const float4*)(Ci + (size_t)o * 2048 + h);
        float4 vl = *(const float4*)(v_log + h);
        float4 tl = *(const float4*)(th_log + h);
        float mag, ang, wr, wi;
        ushort4 u;
        mag = expf(-expf(vl.x)); ang = expf(tl.x); wr = mag * cosf(ang); wi = mag * sinf(ang);
        u.x = f32_to_bf16(cr.x * wr - ci.x * wi);
        mag = expf(-expf(vl.y)); ang = expf(tl.y); wr = mag * cosf(ang); wi = mag * sinf(ang);
        u.y = f32_to_bf16(cr.y * wr - ci.y * wi);
        mag = expf(-expf(vl.z)); ang = expf(tl.z); wr = mag * cosf(ang); wi = mag * sinf(ang);
        u.z = f32_to_bf16(cr.z * wr - ci.z * wi);
        mag = expf(-expf(vl.w)); ang = expf(tl.w); wr = mag * cosf(ang); wi = mag * sinf(ang);
        u.w = f32_to_bf16(cr.w * wr - ci.w * wi);
        ((ushort4*)Cwbf)[j] = u;
    }
}

// ---------------- reduce: Wmain = bf16(sum_z partials[z]) ----------------
// z order 0..7 — same rounding as all previous passing versions.

__global__ void reduce_only_kernel(const float* __restrict__ partials,
                                   u16* __restrict__ Wmain) {
    int i = blockIdx.x * blockDim.x + threadIdx.x;   // 1024 blocks x 256
    int e = i * 4;
    float4 s = *(const float4*)(partials + e);
#pragma unroll
    for (int z = 1; z < 8; z++) {
        float4 p = *(const float4*)(partials + ((size_t)z << 20) + e);
        s.x += p.x; s.y += p.y; s.z += p.z; s.w += p.w;
    }
    ushort4 u;
    u.x = f32_to_bf16(s.x); u.y = f32_to_bf16(s.y);
    u.z = f32_to_bf16(s.z); u.w = f32_to_bf16(s.w);
    ((ushort4*)Wmain)[i] = u;
}

// ---------------- weight GEMM: split-K=8, 128x128 tile, BK=64 ----------------
// partials[bz][m][n] = sum_{k in 512-chunk bz} Ccat[m][k] * Bcat[n][k], K=4096
// NO in-kernel reduction tail: cross-XCD partials hand-off goes through the
// dispatch boundary (round-1 lesson: device-scope fence per block = 4x slowdown).

__global__ __launch_bounds__(256)
void gemm_splitk_kernel(const u16* __restrict__ A, const u16* __restrict__ B,
                        float* __restrict__ partials)
{
    __shared__ __align__(16) u16 ldsA[128 * 64];
    __shared__ __align__(16) u16 ldsB[128 * 64];
    const int K = 4096;

    const int tid = threadIdx.x, wid = tid >> 6, lane = tid & 63;
    const int quad = lane >> 4, l16 = lane & 15;
    const int wm = wid >> 1, wn = wid & 1;
    const int bm = blockIdx.y, bn = blockIdx.x, bz = blockIdx.z;
    const int kb = bz * 512;

    const u16* gA[4]; const u16* gB[4];
    u16 *lA[4], *lB[4];
#pragma unroll
    for (int t = 0; t < 4; t++) {
        int s = wid * 256 + t * 64 + lane;
        int sr = s >> 3;
        int sj = (s & 7) ^ (sr & 7);
        lA[t] = ldsA + s * 8;
        lB[t] = ldsB + s * 8;
        gA[t] = A + (size_t)(bm * 128 + sr) * K + sj * 8 + kb;
        gB[t] = B + (size_t)(bn * 128 + sr) * K + sj * 8 + kb;
    }

    const f32x4 fz = {0.f, 0.f, 0.f, 0.f};
    f32x4 acc[4][4];
#pragma unroll
    for (int i = 0; i < 4; i++)
#pragma unroll
        for (int j = 0; j < 4; j++) acc[i][j] = fz;

    for (int k0 = 0; k0 < 512; k0 += 64) {
        __syncthreads();
#pragma unroll
        for (int t = 0; t < 4; t++) {
            gld_lds16(gA[t] + k0, lA[t]);
            gld_lds16(gB[t] + k0, lB[t]);
        }
        __syncthreads();
#pragma unroll
        for (int ks = 0; ks < 2; ks++) {
            bf16x8 af[4], bfr[4];
#pragma unroll
            for (int i = 0; i < 4; i++) {
                int r = wm * 64 + i * 16 + l16;
                af[i] = *(const bf16x8*)(ldsA + (r * 8 + ((ks * 4 + quad) ^ (r & 7))) * 8);
            }
#pragma unroll
            for (int j = 0; j < 4; j++) {
                int r = wn * 64 + j * 16 + l16;
                bfr[j] = *(const bf16x8*)(ldsB + (r * 8 + ((ks * 4 + quad) ^ (r & 7))) * 8);
            }
#pragma unroll
            for (int i = 0; i < 4; i++)
#pragma unroll
                for (int j = 0; j < 4; j++)
                    acc[i][j] = __builtin_amdgcn_mfma_f32_16x16x32_bf16(af[i], bfr[j], acc[i][j], 0, 0, 0);
        }
    }

    float* P = partials + ((size_t)bz << 20);
    const int gm = bm * 128 + wm * 64, gn = bn * 128 + wn * 64;
#pragma unroll
    for (int i = 0; i < 4; i++)
#pragma unroll
        for (int j = 0; j < 4; j++) {
            int col = gn + j * 16 + l16;
#pragma unroll
            for (int r = 0; r < 4; r++)
                P[(size_t)(gm + i * 16 + quad * 4 + r) * 1024 + col] = acc[i][j][r];
        }
}

// ---------------- main GEMM (fused f32->bf16 A-cast, 3-deep ring) ----------------
// out[8192,1024] = bf16([x | h_prev]) @ [Wmain | Cwbf]^T, virtual K = 48 tiles of
// 64 (tiles 0..15 from x@Wmain^T, 16..47 from h_prev@Cwbf^T — same accumulation
// order and same RNE cast as all previous passing versions -> identical numerics).
// A is read as f32 DIRECTLY from the kernel inputs and cast in-register during
// staging (T14 issue-early/write-late): pre-casting x/h to bf16 cost
// 96R+48W+48R = 192 MB of HBM; direct f32 read costs 96 MB. B (bf16 weights)
// stays on the proven gld_lds path. Every __syncthreads drain (vmcnt 0) is
// covered by the ~2850-cycle compute phase, so no explicit waitcnt asm needed.
// BM=256 BN=128 BK=64, 512 thr (8 waves, 4Mx2N, per-wave 64x64 — frag math
// identical to the proven kernel). Grid = 256 blocks = 1 block/CU; bm = id&31
// so the 8 bn-sharers of an A-strip are co-XCD (id%8 == bm%8).

__global__ __launch_bounds__(512)
void gemm_main_kernel(const float* __restrict__ Xf, const float* __restrict__ Hf,
                      const u16* __restrict__ Bw,  const u16* __restrict__ Bcw,
                      float* __restrict__ out)
{
    // per buffer: A = 256x64 bf16 (16384 u16), B = 128x64 (8192 u16) at offset 16384
    __shared__ __align__(16) u16 lds[3][24576];

    const int tid = threadIdx.x, wid = tid >> 6, lane = tid & 63;
    const int quad = lane >> 4, l16 = lane & 15;
    const int wm = wid >> 1, wn = wid & 1;          // 4 M-waves x 2 N-waves
    const int id = blockIdx.x;
    const int bm = id & 31, bn = id >> 5;

    // staging slot geometry (per thread): A = 4 chunks x 512 thr, B = 2 issues
    int srA[4], sjA[4], srB[2], sjB[2];
#pragma unroll
    for (int q = 0; q < 4; q++) {
        int s = q * 512 + tid;
        srA[q] = s >> 3;
        sjA[q] = (s & 7) ^ (srA[q] & 7);
    }
#pragma unroll
    for (int q = 0; q < 2; q++) {
        int s = q * 512 + tid;
        srB[q] = s >> 3;
        sjB[q] = (s & 7) ^ (srB[q] & 7);
    }

    u16* buf0 = &lds[0][0];
    u16* buf1 = &lds[1][0];
    u16* buf2 = &lds[2][0];

    const f32x4 fz = {0.f, 0.f, 0.f, 0.f};
    f32x4 acc[4][4];
#pragma unroll
    for (int i = 0; i < 4; i++)
#pragma unroll
        for (int j = 0; j < 4; j++) acc[i][j] = fz;

    // B staging: async gld_lds into buf's B region (2 issues/thread)
    auto stageB = [&](int tt, u16* buf) {
        const u16* Bb; int KS, koff;
        if (tt < 16) { Bb = Bw;  KS = 1024; koff = tt * 64; }
        else         { Bb = Bcw; KS = 2048; koff = (tt - 16) * 64; }
#pragma unroll
        for (int q = 0; q < 2; q++)
            gld_lds16(Bb + (size_t)(bn * 128 + srB[q]) * KS + koff + sjB[q] * 8,
                      buf + 16384 + (q * 512 + tid) * 8);
    };

    // A loads: 8x float4 from f32 source into regs (issued early, consumed late)
    float4 areg[4][2];
    auto loadA = [&](int tt) {
        const float* Af; int KS, koff;
        if (tt < 16) { Af = Xf; KS = 1024; koff = tt * 64; }
        else         { Af = Hf; KS = 2048; koff = (tt - 16) * 64; }
#pragma unroll
        for (int q = 0; q < 4; q++) {
            const float* p = Af + (size_t)(bm * 256 + srA[q]) * KS + koff + sjA[q] * 8;
            areg[q][0] = *(const float4*)(p);
            areg[q][1] = *(const float4*)(p + 4);
        }
    };

    // cast + ds_write_b128 into buf's A region (compiler auto-waits areg deps)
    auto writeA = [&](u16* buf) {
#pragma unroll
        for (int q = 0; q < 4; q++) {
            bf16x8 v;
            v[0] = (short)f32_to_bf16(areg[q][0].x);
            v[1] = (short)f32_to_bf16(areg[q][0].y);
            v[2] = (short)f32_to_bf16(areg[q][0].z);
            v[3] = (short)f32_to_bf16(areg[q][0].w);
            v[4] = (short)f32_to_bf16(areg[q][1].x);
            v[5] = (short)f32_to_bf16(areg[q][1].y);
            v[6] = (short)f32_to_bf16(areg[q][1].z);
            v[7] = (short)f32_to_bf16(areg[q][1].w);
            *(bf16x8*)(buf + ((size_t)q * 512 + tid) * 8) = v;
        }
    };

    // compute one K-tile (32 MFMA/wave, ks = 0,1) from buf
    auto compute = [&](const u16* buf) {
#pragma unroll
        for (int ks = 0; ks < 2; ks++) {
            bf16x8 af[4], bfr[4];
#pragma unroll
            for (int i = 0; i < 4; i++) {
                int r = wm * 64 + i * 16 + l16;
                af[i] = *(const bf16x8*)(buf + (r * 8 + ((ks * 4 + quad) ^ (r & 7))) * 8);
            }
#pragma unroll
            for (int j = 0; j < 4; j++) {
                int r = wn * 64 + j * 16 + l16;
                bfr[j] = *(const bf16x8*)(buf + 16384 + (r * 8 + ((ks * 4 + quad) ^ (r & 7))) * 8);
            }
            __builtin_amdgcn_s_setprio(1);
#pragma unroll
            for (int i = 0; i < 4; i++)
#pragma unroll
                for (int j = 0; j < 4; j++)
                    acc[i][j] = __builtin_amdgcn_mfma_f32_16x16x32_bf16(af[i], bfr[j], acc[i][j], 0, 0, 0);
            __builtin_amdgcn_s_setprio(0);
        }
    };

    // prologue: tiles 0,1 fully staged (writeA auto-waits its loads)
    stageB(0, buf0); loadA(0); writeA(buf0);
    stageB(1, buf1); loadA(1); writeA(buf1);
    __syncthreads();

    // steady state: phase p computes tile p from buf[p%3], stages p+2 into
    // buf[(p+2)%3]. Staged buf was last read at phase p-2 (barrier-separated).
    // 15 triples = phases 0..44 (stage tiles 2..46).
#pragma unroll 1
    for (int it = 0; it < 15; it++) {
        stageB(3 * it + 2, buf2); loadA(3 * it + 2); compute(buf0); writeA(buf2); __syncthreads();
        stageB(3 * it + 3, buf0); loadA(3 * it + 3); compute(buf1); writeA(buf0); __syncthreads();
        stageB(3 * it + 4, buf1); loadA(3 * it + 4); compute(buf2); writeA(buf1); __syncthreads();
    }
    // phase 45: compute tile 45 (buf0), stage tile 47 into buf2
    stageB(47, buf2); loadA(47); compute(buf0); writeA(buf2); __syncthreads();
    // phases 46,47: compute only (no staging; no further hazards -> no barriers)
    compute(buf1);
    compute(buf2);

    const int gm = bm * 256 + wm * 64, gn = bn * 128 + wn * 64;
#pragma unroll
    for (int i = 0; i < 4; i++)
#pragma unroll
        for (int j = 0; j < 4; j++) {
            int col = gn + j * 16 + l16;
#pragma unroll
            for (int r = 0; r < 4; r++)
                out[(size_t)(gm + i * 16 + quad * 4 + r) * 1024 + col] = acc[i][j][r];
        }
}

// ---------------- launch ----------------

extern "C" void kernel_launch(void* const* d_in, const int* in_sizes, int n_in,
                              void* d_out, int out_size, void* d_ws, size_t ws_size,
                              hipStream_t stream)
{
    const float* x      = (const float*)d_in[0];
    const float* h_prev = (const float*)d_in[1];
    const float* Br     = (const float*)d_in[2];
    const float* Bi     = (const float*)d_in[3];
    const float* Cr     = (const float*)d_in[4];
    const float* Ci     = (const float*)d_in[5];
    const float* v_log  = (const float*)d_in[6];
    const float* th_log = (const float*)d_in[7];
    float* out = (float*)d_out;

    const size_t MB = 1024 * 1024;
    if (ws_size < 54 * MB) return;

    char* ws = (char*)d_ws;
    u16*   Ccat     = (u16*)ws;                   // [1024,4096] bf16
    u16*   Bcat     = (u16*)(ws + 8 * MB);        // [1024,4096] bf16 = [BrT|BiT]
    float* partials = (float*)(ws + 16 * MB);     // [8][1024][1024] f32
    u16*   Wmain    = (u16*)(ws + 48 * MB);       // [1024,1024] bf16
    u16*   Cwbf     = (u16*)(ws + 50 * MB);       // [1024,2048] bf16

    // 1) prep: Ccat=[Cr|-Ci], Bcat=[Br^T|Bi^T], Cwbf=bf16(Cr*wr-Ci*wi)
    prep_kernel<<<10240, 256, 0, stream>>>(Cr, Ci, Br, Bi, v_log, th_log,
                                           Ccat, Bcat, Cwbf);
    // 2) partials = Ccat @ Bcat^T (split-K=8, 512 blocks, no tail)
    gemm_splitk_kernel<<<dim3(8, 8, 8), 256, 0, stream>>>(Ccat, Bcat, partials);
    // 3) Wmain = bf16(sum partials)
    reduce_only_kernel<<<1024, 256, 0, stream>>>(partials, Wmain);
    // 4) out = bf16([x | h_prev]) @ [Wmain | Cwbf]^T  (A cast fused into staging)
    gemm_main_kernel<<<256, 512, 0, stream>>>(x, h_prev, Wmain, Cwbf, out);
}

// Round 5
// 254.445 us; speedup vs baseline: 1.1437x; 1.1437x over previous
//
#include <hip/hip_runtime.h>
#include <stdint.h>

typedef unsigned short u16;
typedef short bf16x8 __attribute__((ext_vector_type(8)));   // 8 bf16 in 4 VGPRs
typedef float f32x4 __attribute__((ext_vector_type(4)));

typedef void as1_void __attribute__((address_space(1)));
typedef void as3_void __attribute__((address_space(3)));

__device__ inline u16 f32_to_bf16(float f) {
    uint32_t u = __builtin_bit_cast(uint32_t, f);
    u += 0x7fffu + ((u >> 16) & 1u);   // RNE (finite values only)
    return (u16)(u >> 16);
}

__device__ inline void gld_lds16(const void* g, void* l) {
    // async global->LDS, 16B/lane; HW dest = wave-uniform base + lane*16
    __builtin_amdgcn_global_load_lds((as1_void*)g, (as3_void*)l, 16, 0, 0);
}

// LDS tile layout (all GEMMs): R rows x 64 cols bf16, stored as R*8 chunks of
// 16B. Global (row, colchunk j) lives at chunk slot row*8 + (j ^ (row&7)).
// The XOR swizzle spreads same-column frag reads across all 32 banks (2-way max,
// free per m136) while keeping each staging issue 64 lane-contiguous slots.
// (Measured SQ_LDS_BANK_CONFLICT = 0 with this scheme.)

// ---------------- merged prep kernel ----------------
// blocks [0,4096):     Ccat[o][k] = [Cr | -Ci]  row-major [1024][4096] bf16
// blocks [4096,8192):  Bcat[c][colOff+r] = bf16(src[r][c]) (32x32 LDS transpose)
// blocks [8192,10240): Cwbf[o][h] = bf16(Cr*wr - Ci*wi), w recomputed inline

__global__ void prep_kernel(const float* __restrict__ Cr, const float* __restrict__ Ci,
                            const float* __restrict__ Br, const float* __restrict__ Bi,
                            const float* __restrict__ v_log, const float* __restrict__ th_log,
                            u16* __restrict__ Ccat, u16* __restrict__ Bcat,
                            u16* __restrict__ Cwbf)
{
    __shared__ float t[32][33];
    const int b = blockIdx.x, tid = threadIdx.x;

    if (b < 4096) {
        // ---- pack Ccat = [Cr | -Ci] ----
        int i = b * 256 + tid;
        int e = i * 4;
        int o = e >> 12;
        int k = e & 4095;
        float4 f; float s;
        if (k < 2048) { f = *(const float4*)(Cr + (size_t)o * 2048 + k);          s =  1.f; }
        else          { f = *(const float4*)(Ci + (size_t)o * 2048 + (k - 2048)); s = -1.f; }
        ushort4 u;
        u.x = f32_to_bf16(s * f.x); u.y = f32_to_bf16(s * f.y);
        u.z = f32_to_bf16(s * f.z); u.w = f32_to_bf16(s * f.w);
        ((ushort4*)Ccat)[i] = u;
    } else if (b < 8192) {
        // ---- transpose-cast Bcat = [Br^T | Bi^T] ----
        int b2 = b - 4096;
        const float* src = (b2 & 2048) ? Bi : Br;
        int colOff = (b2 & 2048) ? 2048 : 0;
        int c0 = (b2 & 31) * 32, r0 = ((b2 >> 5) & 63) * 32;
        int tx = tid & 31, ty = tid >> 5;   // 32 x 8
#pragma unroll
        for (int j = 0; j < 4; j++)
            t[ty + j * 8][tx] = src[(size_t)(r0 + ty + j * 8) * 1024 + c0 + tx];
        __syncthreads();
#pragma unroll
        for (int j = 0; j < 4; j++)
            Bcat[(size_t)(c0 + ty + j * 8) * 4096 + colOff + r0 + tx] =
                f32_to_bf16(t[tx][ty + j * 8]);
    } else {
        // ---- Cwbf = bf16(Cr*wr - Ci*wi); w recomputed per element (cheap trans) ----
        int j = (b - 8192) * 256 + tid;
        int e = j * 4;
        int o = e >> 11;
        int h = e & 2047;
        float4 cr = *(const float4*)(Cr + (size_t)o * 2048 + h);
        float4 ci = *(const float4*)(Ci + (size_t)o * 2048 + h);
        float4 vl = *(const float4*)(v_log + h);
        float4 tl = *(const float4*)(th_log + h);
        float mag, ang, wr, wi;
        ushort4 u;
        mag = expf(-expf(vl.x)); ang = expf(tl.x); wr = mag * cosf(ang); wi = mag * sinf(ang);
        u.x = f32_to_bf16(cr.x * wr - ci.x * wi);
        mag = expf(-expf(vl.y)); ang = expf(tl.y); wr = mag * cosf(ang); wi = mag * sinf(ang);
        u.y = f32_to_bf16(cr.y * wr - ci.y * wi);
        mag = expf(-expf(vl.z)); ang = expf(tl.z); wr = mag * cosf(ang); wi = mag * sinf(ang);
        u.z = f32_to_bf16(cr.z * wr - ci.z * wi);
        mag = expf(-expf(vl.w)); ang = expf(tl.w); wr = mag * cosf(ang); wi = mag * sinf(ang);
        u.w = f32_to_bf16(cr.w * wr - ci.w * wi);
        ((ushort4*)Cwbf)[j] = u;
    }
}

// ---------------- GEMM block body for the weight GEMM (shared) ----------------
// partials[bz][m][n] = sum_{k in 512-chunk bz} Ccat[m][k] * Bcat[n][k], K=4096.
// 128x128 tile, BK=64, 256 thr. Identical math/order to all passing versions.

__device__ __forceinline__
void splitk_block(const u16* __restrict__ A, const u16* __restrict__ B,
                  float* __restrict__ partials,
                  int bm, int bn, int bz, int tid,
                  u16* ldsA, u16* ldsB)
{
    const int K = 4096;
    const int wid = tid >> 6, lane = tid & 63;
    const int quad = lane >> 4, l16 = lane & 15;
    const int wm = wid >> 1, wn = wid & 1;
    const int kb = bz * 512;

    const u16* gA[4]; const u16* gB[4];
    u16 *lA[4], *lB[4];
#pragma unroll
    for (int t = 0; t < 4; t++) {
        int s = wid * 256 + t * 64 + lane;
        int sr = s >> 3;
        int sj = (s & 7) ^ (sr & 7);
        lA[t] = ldsA + s * 8;
        lB[t] = ldsB + s * 8;
        gA[t] = A + (size_t)(bm * 128 + sr) * K + sj * 8 + kb;
        gB[t] = B + (size_t)(bn * 128 + sr) * K + sj * 8 + kb;
    }

    const f32x4 fz = {0.f, 0.f, 0.f, 0.f};
    f32x4 acc[4][4];
#pragma unroll
    for (int i = 0; i < 4; i++)
#pragma unroll
        for (int j = 0; j < 4; j++) acc[i][j] = fz;

    for (int k0 = 0; k0 < 512; k0 += 64) {
        __syncthreads();
#pragma unroll
        for (int t = 0; t < 4; t++) {
            gld_lds16(gA[t] + k0, lA[t]);
            gld_lds16(gB[t] + k0, lB[t]);
        }
        __syncthreads();
#pragma unroll
        for (int ks = 0; ks < 2; ks++) {
            bf16x8 af[4], bfr[4];
#pragma unroll
            for (int i = 0; i < 4; i++) {
                int r = wm * 64 + i * 16 + l16;
                af[i] = *(const bf16x8*)(ldsA + (r * 8 + ((ks * 4 + quad) ^ (r & 7))) * 8);
            }
#pragma unroll
            for (int j = 0; j < 4; j++) {
                int r = wn * 64 + j * 16 + l16;
                bfr[j] = *(const bf16x8*)(ldsB + (r * 8 + ((ks * 4 + quad) ^ (r & 7))) * 8);
            }
#pragma unroll
            for (int i = 0; i < 4; i++)
#pragma unroll
                for (int j = 0; j < 4; j++)
                    acc[i][j] = __builtin_amdgcn_mfma_f32_16x16x32_bf16(af[i], bfr[j], acc[i][j], 0, 0, 0);
        }
    }

    float* P = partials + ((size_t)bz << 20);
    const int gm = bm * 128 + wm * 64, gn = bn * 128 + wn * 64;
#pragma unroll
    for (int i = 0; i < 4; i++)
#pragma unroll
        for (int j = 0; j < 4; j++) {
            int col = gn + j * 16 + l16;
#pragma unroll
            for (int r = 0; r < 4; r++)
                P[(size_t)(gm + i * 16 + quad * 4 + r) * 1024 + col] = acc[i][j][r];
        }
}

// plain splitk (fallback tiers)
__global__ __launch_bounds__(256)
void gemm_splitk_kernel(const u16* __restrict__ A, const u16* __restrict__ B,
                        float* __restrict__ partials)
{
    __shared__ __align__(16) u16 ldsA[128 * 64];
    __shared__ __align__(16) u16 ldsB[128 * 64];
    splitk_block(A, B, partials, blockIdx.y, blockIdx.x, blockIdx.z, threadIdx.x,
                 ldsA, ldsB);
}

// splitk + overlapped x/h cast (big2 tier).
// blocks [0,512): the 512 GEMM blocks (id -> bn=id&7, bm=(id>>3)&7, bz=id>>6);
// blocks [512, 2560): grid-stride cast of x (2097152 float4) then h_prev
// (4194304 float4) into x_bf / hp_bf. 32 KB LDS keeps cast blocks co-resident
// (~5 blocks/CU) so the BW-bound cast rides under the compute-bound GEMM
// (splitk alone is only ~11% HBM). Writes nothing the GEMM blocks touch.
__global__ __launch_bounds__(256)
void splitk_cast_kernel(const u16* __restrict__ A, const u16* __restrict__ B,
                        float* __restrict__ partials,
                        const float* __restrict__ x, const float* __restrict__ h_prev,
                        u16* __restrict__ x_bf, u16* __restrict__ hp_bf)
{
    __shared__ __align__(16) u16 ldsA[128 * 64];
    __shared__ __align__(16) u16 ldsB[128 * 64];
    const int id = blockIdx.x, tid = threadIdx.x;
    if (id < 512) {
        splitk_block(A, B, partials, (id >> 3) & 7, id & 7, id >> 6, tid,
                     ldsA, ldsB);
        return;
    }
    const int cid = id - 512;                 // [0, 2048)
    const int n4x = 8192 * 1024 / 4;          // 2097152
    const int n4  = n4x + 8192 * 2048 / 4;    // 6291456
#pragma unroll 1
    for (int j = cid * 256 + tid; j < n4; j += 2048 * 256) {
        float4 f; ushort4 o;
        if (j < n4x) { f = ((const float4*)x)[j]; }
        else         { f = ((const float4*)h_prev)[j - n4x]; }
        o.x = f32_to_bf16(f.x); o.y = f32_to_bf16(f.y);
        o.z = f32_to_bf16(f.z); o.w = f32_to_bf16(f.w);
        if (j < n4x) ((ushort4*)x_bf)[j] = o;
        else         ((ushort4*)hp_bf)[j - n4x] = o;
    }
}

// ---------------- reduce + cast variants ----------------

// big tier (86-102 MB): merged reduce + both casts (R2-proven body)
__global__ void reduce_cast_kernel(const float* __restrict__ partials,
                                   const float* __restrict__ x,
                                   const float* __restrict__ h_prev,
                                   u16* __restrict__ Wmain,
                                   u16* __restrict__ x_bf,
                                   u16* __restrict__ hp_bf)
{
    const int b = blockIdx.x, tid = threadIdx.x;
    if (b < 1024) {
        int i = b * 256 + tid;
        int e = i * 4;
        float4 s = *(const float4*)(partials + e);
#pragma unroll
        for (int z = 1; z < 8; z++) {
            float4 p = *(const float4*)(partials + ((size_t)z << 20) + e);
            s.x += p.x; s.y += p.y; s.z += p.z; s.w += p.w;
        }
        ushort4 u;
        u.x = f32_to_bf16(s.x); u.y = f32_to_bf16(s.y);
        u.z = f32_to_bf16(s.z); u.w = f32_to_bf16(s.w);
        ((ushort4*)Wmain)[i] = u;
    } else if (b < 9216) {
        int i = (b - 1024) * 256 + tid;
        float4 f = ((const float4*)x)[i];
        ushort4 o;
        o.x = f32_to_bf16(f.x); o.y = f32_to_bf16(f.y);
        o.z = f32_to_bf16(f.z); o.w = f32_to_bf16(f.w);
        ((ushort4*)x_bf)[i] = o;
    } else {
        int i = (b - 9216) * 256 + tid;
        float4 f = ((const float4*)h_prev)[i];
        ushort4 o;
        o.x = f32_to_bf16(f.x); o.y = f32_to_bf16(f.y);
        o.z = f32_to_bf16(f.z); o.w = f32_to_bf16(f.w);
        ((ushort4*)hp_bf)[i] = o;
    }
}

// Wmain = bf16(sum_z partials[z]); z order 0..7 (same rounding as ever)
__global__ void reduce_only_kernel(const float* __restrict__ partials,
                                   u16* __restrict__ Wmain) {
    int i = blockIdx.x * blockDim.x + threadIdx.x;   // 1024 blocks x 256
    int e = i * 4;
    float4 s = *(const float4*)(partials + e);
#pragma unroll
    for (int z = 1; z < 8; z++) {
        float4 p = *(const float4*)(partials + ((size_t)z << 20) + e);
        s.x += p.x; s.y += p.y; s.z += p.z; s.w += p.w;
    }
    ushort4 u;
    u.x = f32_to_bf16(s.x); u.y = f32_to_bf16(s.y);
    u.z = f32_to_bf16(s.z); u.w = f32_to_bf16(s.w);
    ((ushort4*)Wmain)[i] = u;
}

// small tier: dst[0..16MB) = bf16(x), dst[16MB..48MB) = bf16(h_prev) (adjacent)
__global__ void cast_both_kernel(const float* __restrict__ x,
                                 const float* __restrict__ h_prev,
                                 u16* __restrict__ dst) {
    const int n4x = 8192 * 1024 / 4;     // 2097152
    int i = blockIdx.x * blockDim.x + threadIdx.x;
    float4 f = (i < n4x) ? ((const float4*)x)[i] : ((const float4*)h_prev)[i - n4x];
    ushort4 o;
    o.x = f32_to_bf16(f.x); o.y = f32_to_bf16(f.y);
    o.z = f32_to_bf16(f.z); o.w = f32_to_bf16(f.w);
    ((ushort4*)dst)[i] = o;
}

// ---------------- main GEMM (R3-proven: 256x128 tile, 3-deep ring) ----------------
// out[8192,1024] = [x_bf | hp_bf] @ [Wmain | Cwbf]^T, virtual K = 48 tiles of 64
// (tiles 0..15 from x@Wmain^T, 16..47 from hp@Cwbf^T — same accumulation order
// as all passing versions -> identical numerics).
// BM=256 BN=128 BK=64, 512 thr (8 waves, 4Mx2N, per-wave 64x64). 3-deep LDS ring
// (144 KB), lookahead-2 staging, counted vmcnt(6) (never drain 0 in loop),
// raw s_barrier + compiler fences, setprio around MFMA clusters. Grid = 256
// blocks = 1/CU; bm = id&31 so the 8 bn-sharers of an A-strip are co-XCD.

__global__ __launch_bounds__(512)
void gemm_main_kernel(const u16* __restrict__ Axb, const u16* __restrict__ Ahb,
                      const u16* __restrict__ Bw,  const u16* __restrict__ Bcw,
                      float* __restrict__ out)
{
    // per buffer: A = 256x64 bf16 (16384 u16), B = 128x64 (8192 u16) at offset 16384
    __shared__ __align__(16) u16 lds[3][24576];

    const int tid = threadIdx.x, wid = tid >> 6, lane = tid & 63;
    const int quad = lane >> 4, l16 = lane & 15;
    const int wm = wid >> 1, wn = wid & 1;          // 4 M-waves x 2 N-waves
    const int id = blockIdx.x;
    const int bm = id & 31, bn = id >> 5;

    // staging slot geometry (per thread): A = 4 issues x 512 thr, B = 2 issues
    int srA[4], sjA[4], srB[2], sjB[2];
#pragma unroll
    for (int q = 0; q < 4; q++) {
        int s = q * 512 + tid;
        srA[q] = s >> 3;
        sjA[q] = (s & 7) ^ (srA[q] & 7);
    }
#pragma unroll
    for (int q = 0; q < 2; q++) {
        int s = q * 512 + tid;
        srB[q] = s >> 3;
        sjB[q] = (s & 7) ^ (srB[q] & 7);
    }

    u16* buf0 = &lds[0][0];
    u16* buf1 = &lds[1][0];
    u16* buf2 = &lds[2][0];

    const f32x4 fz = {0.f, 0.f, 0.f, 0.f};
    f32x4 acc[4][4];
#pragma unroll
    for (int i = 0; i < 4; i++)
#pragma unroll
        for (int j = 0; j < 4; j++) acc[i][j] = fz;

    // stage K-tile tt (0..47) into buf: 6 gld_lds per thread-group (4 A + 2 B)
    auto stage = [&](int tt, u16* buf) {
        const u16* Ab; const u16* Bb; int KS, koff;
        if (tt < 16) { Ab = Axb; Bb = Bw;  KS = 1024; koff = tt * 64; }
        else         { Ab = Ahb; Bb = Bcw; KS = 2048; koff = (tt - 16) * 64; }
#pragma unroll
        for (int q = 0; q < 4; q++)
            gld_lds16(Ab + (size_t)(bm * 256 + srA[q]) * KS + koff + sjA[q] * 8,
                      buf + (q * 512 + tid) * 8);
#pragma unroll
        for (int q = 0; q < 2; q++)
            gld_lds16(Bb + (size_t)(bn * 128 + srB[q]) * KS + koff + sjB[q] * 8,
                      buf + 16384 + (q * 512 + tid) * 8);
    };

    // compute one K-tile (32 MFMA/wave, ks = 0,1) from buf
    auto compute = [&](const u16* buf) {
#pragma unroll
        for (int ks = 0; ks < 2; ks++) {
            bf16x8 af[4], bfr[4];
#pragma unroll
            for (int i = 0; i < 4; i++) {
                int r = wm * 64 + i * 16 + l16;
                af[i] = *(const bf16x8*)(buf + (r * 8 + ((ks * 4 + quad) ^ (r & 7))) * 8);
            }
#pragma unroll
            for (int j = 0; j < 4; j++) {
                int r = wn * 64 + j * 16 + l16;
                bfr[j] = *(const bf16x8*)(buf + 16384 + (r * 8 + ((ks * 4 + quad) ^ (r & 7))) * 8);
            }
            __builtin_amdgcn_s_setprio(1);
#pragma unroll
            for (int i = 0; i < 4; i++)
#pragma unroll
                for (int j = 0; j < 4; j++)
                    acc[i][j] = __builtin_amdgcn_mfma_f32_16x16x32_bf16(af[i], bfr[j], acc[i][j], 0, 0, 0);
            __builtin_amdgcn_s_setprio(0);
        }
    };

#define PUBLISH(N)                                          \
    asm volatile("s_waitcnt vmcnt(" #N ")" ::: "memory");   \
    __builtin_amdgcn_s_barrier();                           \
    asm volatile("" ::: "memory")

    // prologue: stage tiles 0,1; publish tile 0 (tile 1 still in flight)
    stage(0, buf0);
    stage(1, buf1);
    PUBLISH(6);

    // steady state: 15 triples, tiles 0..44; stage lookahead-2 (tiles 2..46)
#pragma unroll 1
    for (int it = 0; it < 15; it++) {
        stage(3 * it + 2, buf2); compute(buf0); PUBLISH(6);
        stage(3 * it + 3, buf0); compute(buf1); PUBLISH(6);
        stage(3 * it + 4, buf1); compute(buf2); PUBLISH(6);
    }
    // tail: tiles 45 (buf0), 46 (buf1), 47 (buf2)
    stage(47, buf2); compute(buf0); PUBLISH(6);
    compute(buf1); PUBLISH(0);
    compute(buf2);
#undef PUBLISH

    const int gm = bm * 256 + wm * 64, gn = bn * 128 + wn * 64;
#pragma unroll
    for (int i = 0; i < 4; i++)
#pragma unroll
        for (int j = 0; j < 4; j++) {
            int col = gn + j * 16 + l16;
#pragma unroll
            for (int r = 0; r < 4; r++)
                out[(size_t)(gm + i * 16 + quad * 4 + r) * 1024 + col] = acc[i][j][r];
        }
}

// ---------------- launch ----------------

extern "C" void kernel_launch(void* const* d_in, const int* in_sizes, int n_in,
                              void* d_out, int out_size, void* d_ws, size_t ws_size,
                              hipStream_t stream)
{
    const float* x      = (const float*)d_in[0];
    const float* h_prev = (const float*)d_in[1];
    const float* Br     = (const float*)d_in[2];
    const float* Bi     = (const float*)d_in[3];
    const float* Cr     = (const float*)d_in[4];
    const float* Ci     = (const float*)d_in[5];
    const float* v_log  = (const float*)d_in[6];
    const float* th_log = (const float*)d_in[7];
    float* out = (float*)d_out;

    const size_t MB = 1024 * 1024;
    if (ws_size < 54 * MB) return;
    const bool big2 = (ws_size >= 102 * MB);  // non-aliased x_bf+hp_bf -> overlapped cast
    const bool big  = (ws_size >= 86 * MB);   // non-aliased hp_bf -> merged reduce+cast

    char* ws = (char*)d_ws;
    u16*   Ccat     = (u16*)ws;                   // [1024,4096] bf16
    u16*   Bcat     = (u16*)(ws + 8 * MB);        // [1024,4096] bf16 = [BrT|BiT]
    float* partials = (float*)(ws + 16 * MB);     // [8][1024][1024] f32
    u16*   Wmain    = (u16*)(ws + 48 * MB);       // [1024,1024] bf16
    u16*   Cwbf     = (u16*)(ws + 50 * MB);       // [1024,2048] bf16
    // x_bf: big2 -> fresh @54MB (cast runs concurrently with live Ccat/Bcat);
    //       else  -> aliases Ccat/Bcat (dead once splitk done; cast runs after).
    u16*   x_bf     = big2 ? (u16*)(ws + 54 * MB) : (u16*)ws;
    // hp_bf: big2 -> fresh @70MB; big -> fresh @54MB; small -> aliases partials.
    u16*   hp_bf    = big2 ? (u16*)(ws + 70 * MB)
                    : big  ? (u16*)(ws + 54 * MB)
                           : (u16*)(ws + 16 * MB);

    // 1) prep: Ccat=[Cr|-Ci], Bcat=[Br^T|Bi^T], Cwbf=bf16(Cr*wr-Ci*wi)
    prep_kernel<<<10240, 256, 0, stream>>>(Cr, Ci, Br, Bi, v_log, th_log,
                                           Ccat, Bcat, Cwbf);
    if (big2) {
        // 2) partials = Ccat @ Bcat^T  +  overlapped x/h -> bf16 cast
        splitk_cast_kernel<<<2560, 256, 0, stream>>>(Ccat, Bcat, partials,
                                                     x, h_prev, x_bf, hp_bf);
        // 3) Wmain = bf16(sum partials)
        reduce_only_kernel<<<1024, 256, 0, stream>>>(partials, Wmain);
    } else {
        // 2) partials = Ccat @ Bcat^T (split-K=8, 512 blocks, no tail)
        gemm_splitk_kernel<<<dim3(8, 8, 8), 256, 0, stream>>>(Ccat, Bcat, partials);
        // 3) Wmain = bf16(sum partials); x/h_prev -> bf16
        if (big) {
            reduce_cast_kernel<<<25600, 256, 0, stream>>>(partials, x, h_prev,
                                                          Wmain, x_bf, hp_bf);
        } else {
            reduce_only_kernel<<<1024, 256, 0, stream>>>(partials, Wmain);
            cast_both_kernel<<<24576, 256, 0, stream>>>(x, h_prev, x_bf);
        }
    }
    // 4) out = [x_bf | hp_bf] @ [Wmain | Cwbf]^T  (256x128 tile, 3-deep pipeline)
    gemm_main_kernel<<<256, 512, 0, stream>>>(x_bf, hp_bf, Wmain, Cwbf, out);
}

// Round 6
// 242.207 us; speedup vs baseline: 1.2015x; 1.0505x over previous
//
#include <hip/hip_runtime.h>
#include <stdint.h>

typedef unsigned short u16;
typedef short bf16x8 __attribute__((ext_vector_type(8)));   // 8 bf16 in 4 VGPRs
typedef float f32x4 __attribute__((ext_vector_type(4)));

typedef void as1_void __attribute__((address_space(1)));
typedef void as3_void __attribute__((address_space(3)));

__device__ inline u16 f32_to_bf16(float f) {
    uint32_t u = __builtin_bit_cast(uint32_t, f);
    u += 0x7fffu + ((u >> 16) & 1u);   // RNE (finite values only)
    return (u16)(u >> 16);
}

__device__ inline void gld_lds16(const void* g, void* l) {
    // async global->LDS, 16B/lane; HW dest = wave-uniform base + lane*16
    __builtin_amdgcn_global_load_lds((as1_void*)g, (as3_void*)l, 16, 0, 0);
}

// LDS tile layout (all GEMMs): R rows x 64 cols bf16, stored as R*8 chunks of
// 16B. Global (row, colchunk j) lives at chunk slot row*8 + (j ^ (row&7)).
// The XOR swizzle spreads same-column frag reads across all 32 banks (2-way max,
// free per m136) while keeping each staging issue 64 lane-contiguous slots.
// (Measured SQ_LDS_BANK_CONFLICT = 0 with this scheme.)

// ---------------- merged prep kernel ----------------
// blocks [0,2048):    read Cr,Ci once at (o,h); write Ccat[o][h]=bf16(Cr),
//                     Ccat[o][2048+h]=bf16(-Ci), Cwbf[o][h]=bf16(Cr*wr-Ci*wi)
//                     (w recomputed inline — same expressions as ever)
// blocks [2048,6144): Bcat[c][colOff+r] = bf16(src[r][c]) (32x32 LDS transpose)

__global__ void prep_kernel(const float* __restrict__ Cr, const float* __restrict__ Ci,
                            const float* __restrict__ Br, const float* __restrict__ Bi,
                            const float* __restrict__ v_log, const float* __restrict__ th_log,
                            u16* __restrict__ Ccat, u16* __restrict__ Bcat,
                            u16* __restrict__ Cwbf)
{
    __shared__ float t[32][33];
    const int b = blockIdx.x, tid = threadIdx.x;

    if (b < 2048) {
        // ---- fused: Ccat = [Cr | -Ci]  +  Cwbf = bf16(Cr*wr - Ci*wi) ----
        int i = b * 256 + tid;            // float4 index over [1024][2048]
        int e = i * 4;
        int o = e >> 11;
        int h = e & 2047;
        float4 cr = *(const float4*)(Cr + (size_t)o * 2048 + h);
        float4 ci = *(const float4*)(Ci + (size_t)o * 2048 + h);
        ushort4 ucr, uci, ucw;
        ucr.x = f32_to_bf16(cr.x); ucr.y = f32_to_bf16(cr.y);
        ucr.z = f32_to_bf16(cr.z); ucr.w = f32_to_bf16(cr.w);
        uci.x = f32_to_bf16(-ci.x); uci.y = f32_to_bf16(-ci.y);
        uci.z = f32_to_bf16(-ci.z); uci.w = f32_to_bf16(-ci.w);
        float4 vl = *(const float4*)(v_log + h);
        float4 tl = *(const float4*)(th_log + h);
        float mag, ang, wr, wi;
        mag = expf(-expf(vl.x)); ang = expf(tl.x); wr = mag * cosf(ang); wi = mag * sinf(ang);
        ucw.x = f32_to_bf16(cr.x * wr - ci.x * wi);
        mag = expf(-expf(vl.y)); ang = expf(tl.y); wr = mag * cosf(ang); wi = mag * sinf(ang);
        ucw.y = f32_to_bf16(cr.y * wr - ci.y * wi);
        mag = expf(-expf(vl.z)); ang = expf(tl.z); wr = mag * cosf(ang); wi = mag * sinf(ang);
        ucw.z = f32_to_bf16(cr.z * wr - ci.z * wi);
        mag = expf(-expf(vl.w)); ang = expf(tl.w); wr = mag * cosf(ang); wi = mag * sinf(ang);
        ucw.w = f32_to_bf16(cr.w * wr - ci.w * wi);
        *(ushort4*)(Ccat + (size_t)o * 4096 + h)        = ucr;
        *(ushort4*)(Ccat + (size_t)o * 4096 + 2048 + h) = uci;
        *(ushort4*)(Cwbf + (size_t)o * 2048 + h)        = ucw;
    } else {
        // ---- transpose-cast Bcat = [Br^T | Bi^T] ----
        int b2 = b - 2048;
        const float* src = (b2 & 2048) ? Bi : Br;
        int colOff = (b2 & 2048) ? 2048 : 0;
        int c0 = (b2 & 31) * 32, r0 = ((b2 >> 5) & 63) * 32;
        int tx = tid & 31, ty = tid >> 5;   // 32 x 8
#pragma unroll
        for (int j = 0; j < 4; j++)
            t[ty + j * 8][tx] = src[(size_t)(r0 + ty + j * 8) * 1024 + c0 + tx];
        __syncthreads();
#pragma unroll
        for (int j = 0; j < 4; j++)
            Bcat[(size_t)(c0 + ty + j * 8) * 4096 + colOff + r0 + tx] =
                f32_to_bf16(t[tx][ty + j * 8]);
    }
}

// ---------------- weight GEMM: split-K=4, 128x128 tile, BK=64 ----------------
// partials[bz][m][n] = sum_{k in 1024-chunk bz} Ccat[m][k] * Bcat[n][k], K=4096.
// Grid 8x8x4 = 256 blocks = exactly 1/CU (no second scheduling round).
// NO in-kernel reduction tail: cross-XCD partials hand-off goes through the
// dispatch boundary (R1 lesson: device-scope fence per block = 4x slowdown).

__global__ __launch_bounds__(256)
void gemm_splitk_kernel(const u16* __restrict__ A, const u16* __restrict__ B,
                        float* __restrict__ partials)
{
    __shared__ __align__(16) u16 ldsA[128 * 64];
    __shared__ __align__(16) u16 ldsB[128 * 64];
    const int K = 4096;

    const int tid = threadIdx.x, wid = tid >> 6, lane = tid & 63;
    const int quad = lane >> 4, l16 = lane & 15;
    const int wm = wid >> 1, wn = wid & 1;
    const int bm = blockIdx.y, bn = blockIdx.x, bz = blockIdx.z;
    const int kb = bz * 1024;

    const u16* gA[4]; const u16* gB[4];
    u16 *lA[4], *lB[4];
#pragma unroll
    for (int t = 0; t < 4; t++) {
        int s = wid * 256 + t * 64 + lane;
        int sr = s >> 3;
        int sj = (s & 7) ^ (sr & 7);
        lA[t] = ldsA + s * 8;
        lB[t] = ldsB + s * 8;
        gA[t] = A + (size_t)(bm * 128 + sr) * K + sj * 8 + kb;
        gB[t] = B + (size_t)(bn * 128 + sr) * K + sj * 8 + kb;
    }

    const f32x4 fz = {0.f, 0.f, 0.f, 0.f};
    f32x4 acc[4][4];
#pragma unroll
    for (int i = 0; i < 4; i++)
#pragma unroll
        for (int j = 0; j < 4; j++) acc[i][j] = fz;

    for (int k0 = 0; k0 < 1024; k0 += 64) {
        __syncthreads();
#pragma unroll
        for (int t = 0; t < 4; t++) {
            gld_lds16(gA[t] + k0, lA[t]);
            gld_lds16(gB[t] + k0, lB[t]);
        }
        __syncthreads();
#pragma unroll
        for (int ks = 0; ks < 2; ks++) {
            bf16x8 af[4], bfr[4];
#pragma unroll
            for (int i = 0; i < 4; i++) {
                int r = wm * 64 + i * 16 + l16;
                af[i] = *(const bf16x8*)(ldsA + (r * 8 + ((ks * 4 + quad) ^ (r & 7))) * 8);
            }
#pragma unroll
            for (int j = 0; j < 4; j++) {
                int r = wn * 64 + j * 16 + l16;
                bfr[j] = *(const bf16x8*)(ldsB + (r * 8 + ((ks * 4 + quad) ^ (r & 7))) * 8);
            }
#pragma unroll
            for (int i = 0; i < 4; i++)
#pragma unroll
                for (int j = 0; j < 4; j++)
                    acc[i][j] = __builtin_amdgcn_mfma_f32_16x16x32_bf16(af[i], bfr[j], acc[i][j], 0, 0, 0);
        }
    }

    float* P = partials + ((size_t)bz << 20);
    const int gm = bm * 128 + wm * 64, gn = bn * 128 + wn * 64;
#pragma unroll
    for (int i = 0; i < 4; i++)
#pragma unroll
        for (int j = 0; j < 4; j++) {
            int col = gn + j * 16 + l16;
#pragma unroll
            for (int r = 0; r < 4; r++)
                P[(size_t)(gm + i * 16 + quad * 4 + r) * 1024 + col] = acc[i][j][r];
        }
}

// ---------------- reduce + cast (merged; big tier) ----------------
// blocks [0,1024):        Wmain = bf16(sum_z partials[z]) (z order 0..3)
// blocks [1024,9216):     x_bf  = bf16(x)
// blocks [9216,25600):    hp_bf = bf16(h_prev)
// Launches AFTER splitk (stream order = the fence); hp_bf does not alias partials.

__global__ void reduce_cast_kernel(const float* __restrict__ partials,
                                   const float* __restrict__ x,
                                   const float* __restrict__ h_prev,
                                   u16* __restrict__ Wmain,
                                   u16* __restrict__ x_bf,
                                   u16* __restrict__ hp_bf)
{
    const int b = blockIdx.x, tid = threadIdx.x;
    if (b < 1024) {
        int i = b * 256 + tid;
        int e = i * 4;
        float4 s = *(const float4*)(partials + e);
#pragma unroll
        for (int z = 1; z < 4; z++) {
            float4 p = *(const float4*)(partials + ((size_t)z << 20) + e);
            s.x += p.x; s.y += p.y; s.z += p.z; s.w += p.w;
        }
        ushort4 u;
        u.x = f32_to_bf16(s.x); u.y = f32_to_bf16(s.y);
        u.z = f32_to_bf16(s.z); u.w = f32_to_bf16(s.w);
        ((ushort4*)Wmain)[i] = u;
    } else if (b < 9216) {
        int i = (b - 1024) * 256 + tid;
        float4 f = ((const float4*)x)[i];
        ushort4 o;
        o.x = f32_to_bf16(f.x); o.y = f32_to_bf16(f.y);
        o.z = f32_to_bf16(f.z); o.w = f32_to_bf16(f.w);
        ((ushort4*)x_bf)[i] = o;
    } else {
        int i = (b - 9216) * 256 + tid;
        float4 f = ((const float4*)h_prev)[i];
        ushort4 o;
        o.x = f32_to_bf16(f.x); o.y = f32_to_bf16(f.y);
        o.z = f32_to_bf16(f.z); o.w = f32_to_bf16(f.w);
        ((ushort4*)hp_bf)[i] = o;
    }
}

// ---------------- small-workspace fallbacks ----------------

__global__ void reduce_only_kernel(const float* __restrict__ partials,
                                   u16* __restrict__ Wmain) {
    int i = blockIdx.x * blockDim.x + threadIdx.x;   // 1024 blocks x 256
    int e = i * 4;
    float4 s = *(const float4*)(partials + e);
#pragma unroll
    for (int z = 1; z < 4; z++) {
        float4 p = *(const float4*)(partials + ((size_t)z << 20) + e);
        s.x += p.x; s.y += p.y; s.z += p.z; s.w += p.w;
    }
    ushort4 u;
    u.x = f32_to_bf16(s.x); u.y = f32_to_bf16(s.y);
    u.z = f32_to_bf16(s.z); u.w = f32_to_bf16(s.w);
    ((ushort4*)Wmain)[i] = u;
}

// dst[0..16MB) = bf16(x), dst[16MB..48MB) = bf16(h_prev) (adjacent)
__global__ void cast_both_kernel(const float* __restrict__ x,
                                 const float* __restrict__ h_prev,
                                 u16* __restrict__ dst) {
    const int n4x = 8192 * 1024 / 4;     // 2097152
    int i = blockIdx.x * blockDim.x + threadIdx.x;
    float4 f = (i < n4x) ? ((const float4*)x)[i] : ((const float4*)h_prev)[i - n4x];
    ushort4 o;
    o.x = f32_to_bf16(f.x); o.y = f32_to_bf16(f.y);
    o.z = f32_to_bf16(f.z); o.w = f32_to_bf16(f.w);
    ((ushort4*)dst)[i] = o;
}

// ---------------- main GEMM (R3-proven: 256x128 tile, 3-deep ring) ----------------
// out[8192,1024] = [x_bf | hp_bf] @ [Wmain | Cwbf]^T, virtual K = 48 tiles of 64
// (tiles 0..15 from x@Wmain^T, 16..47 from hp@Cwbf^T — same accumulation order
// as all passing versions -> identical numerics).
// BM=256 BN=128 BK=64, 512 thr (8 waves, 4Mx2N, per-wave 64x64). 3-deep LDS ring
// (144 KB), lookahead-2 staging, counted vmcnt(6) (never drain 0 in loop),
// raw s_barrier + compiler fences, setprio around MFMA clusters. Grid = 256
// blocks = 1/CU; bm = id&31 so the 8 bn-sharers of an A-strip are co-XCD.
// DO NOT co-schedule BW work with this kernel (R4/R5 lessons: any added HBM
// latency lands on the per-tile drain and halves throughput).

__global__ __launch_bounds__(512)
void gemm_main_kernel(const u16* __restrict__ Axb, const u16* __restrict__ Ahb,
                      const u16* __restrict__ Bw,  const u16* __restrict__ Bcw,
                      float* __restrict__ out)
{
    // per buffer: A = 256x64 bf16 (16384 u16), B = 128x64 (8192 u16) at offset 16384
    __shared__ __align__(16) u16 lds[3][24576];

    const int tid = threadIdx.x, wid = tid >> 6, lane = tid & 63;
    const int quad = lane >> 4, l16 = lane & 15;
    const int wm = wid >> 1, wn = wid & 1;          // 4 M-waves x 2 N-waves
    const int id = blockIdx.x;
    const int bm = id & 31, bn = id >> 5;

    // staging slot geometry (per thread): A = 4 issues x 512 thr, B = 2 issues
    int srA[4], sjA[4], srB[2], sjB[2];
#pragma unroll
    for (int q = 0; q < 4; q++) {
        int s = q * 512 + tid;
        srA[q] = s >> 3;
        sjA[q] = (s & 7) ^ (srA[q] & 7);
    }
#pragma unroll
    for (int q = 0; q < 2; q++) {
        int s = q * 512 + tid;
        srB[q] = s >> 3;
        sjB[q] = (s & 7) ^ (srB[q] & 7);
    }

    u16* buf0 = &lds[0][0];
    u16* buf1 = &lds[1][0];
    u16* buf2 = &lds[2][0];

    const f32x4 fz = {0.f, 0.f, 0.f, 0.f};
    f32x4 acc[4][4];
#pragma unroll
    for (int i = 0; i < 4; i++)
#pragma unroll
        for (int j = 0; j < 4; j++) acc[i][j] = fz;

    // stage K-tile tt (0..47) into buf: 6 gld_lds per thread (4 A + 2 B)
    auto stage = [&](int tt, u16* buf) {
        const u16* Ab; const u16* Bb; int KS, koff;
        if (tt < 16) { Ab = Axb; Bb = Bw;  KS = 1024; koff = tt * 64; }
        else         { Ab = Ahb; Bb = Bcw; KS = 2048; koff = (tt - 16) * 64; }
#pragma unroll
        for (int q = 0; q < 4; q++)
            gld_lds16(Ab + (size_t)(bm * 256 + srA[q]) * KS + koff + sjA[q] * 8,
                      buf + (q * 512 + tid) * 8);
#pragma unroll
        for (int q = 0; q < 2; q++)
            gld_lds16(Bb + (size_t)(bn * 128 + srB[q]) * KS + koff + sjB[q] * 8,
                      buf + 16384 + (q * 512 + tid) * 8);
    };

    // compute one K-tile (32 MFMA/wave, ks = 0,1) from buf
    auto compute = [&](const u16* buf) {
#pragma unroll
        for (int ks = 0; ks < 2; ks++) {
            bf16x8 af[4], bfr[4];
#pragma unroll
            for (int i = 0; i < 4; i++) {
                int r = wm * 64 + i * 16 + l16;
                af[i] = *(const bf16x8*)(buf + (r * 8 + ((ks * 4 + quad) ^ (r & 7))) * 8);
            }
#pragma unroll
            for (int j = 0; j < 4; j++) {
                int r = wn * 64 + j * 16 + l16;
                bfr[j] = *(const bf16x8*)(buf + 16384 + (r * 8 + ((ks * 4 + quad) ^ (r & 7))) * 8);
            }
            __builtin_amdgcn_s_setprio(1);
#pragma unroll
            for (int i = 0; i < 4; i++)
#pragma unroll
                for (int j = 0; j < 4; j++)
                    acc[i][j] = __builtin_amdgcn_mfma_f32_16x16x32_bf16(af[i], bfr[j], acc[i][j], 0, 0, 0);
            __builtin_amdgcn_s_setprio(0);
        }
    };

#define PUBLISH(N)                                          \
    asm volatile("s_waitcnt vmcnt(" #N ")" ::: "memory");   \
    __builtin_amdgcn_s_barrier();                           \
    asm volatile("" ::: "memory")

    // prologue: stage tiles 0,1; publish tile 0 (tile 1 still in flight)
    stage(0, buf0);
    stage(1, buf1);
    PUBLISH(6);

    // steady state: 15 triples, tiles 0..44; stage lookahead-2 (tiles 2..46)
#pragma unroll 1
    for (int it = 0; it < 15; it++) {
        stage(3 * it + 2, buf2); compute(buf0); PUBLISH(6);
        stage(3 * it + 3, buf0); compute(buf1); PUBLISH(6);
        stage(3 * it + 4, buf1); compute(buf2); PUBLISH(6);
    }
    // tail: tiles 45 (buf0), 46 (buf1), 47 (buf2)
    stage(47, buf2); compute(buf0); PUBLISH(6);
    compute(buf1); PUBLISH(0);
    compute(buf2);
#undef PUBLISH

    const int gm = bm * 256 + wm * 64, gn = bn * 128 + wn * 64;
#pragma unroll
    for (int i = 0; i < 4; i++)
#pragma unroll
        for (int j = 0; j < 4; j++) {
            int col = gn + j * 16 + l16;
#pragma unroll
            for (int r = 0; r < 4; r++)
                out[(size_t)(gm + i * 16 + quad * 4 + r) * 1024 + col] = acc[i][j][r];
        }
}

// ---------------- launch ----------------

extern "C" void kernel_launch(void* const* d_in, const int* in_sizes, int n_in,
                              void* d_out, int out_size, void* d_ws, size_t ws_size,
                              hipStream_t stream)
{
    const float* x      = (const float*)d_in[0];
    const float* h_prev = (const float*)d_in[1];
    const float* Br     = (const float*)d_in[2];
    const float* Bi     = (const float*)d_in[3];
    const float* Cr     = (const float*)d_in[4];
    const float* Ci     = (const float*)d_in[5];
    const float* v_log  = (const float*)d_in[6];
    const float* th_log = (const float*)d_in[7];
    float* out = (float*)d_out;

    const size_t MB = 1024 * 1024;
    if (ws_size < 54 * MB) return;
    const bool big = (ws_size >= 86 * MB);   // non-aliased hp_bf -> merged reduce+cast

    char* ws = (char*)d_ws;
    u16*   Ccat     = (u16*)ws;                   // [1024,4096] bf16
    u16*   Bcat     = (u16*)(ws + 8 * MB);        // [1024,4096] bf16 = [BrT|BiT]
    float* partials = (float*)(ws + 16 * MB);     // [4][1024][1024] f32 (split-K=4)
    u16*   x_bf     = (u16*)ws;                   // [8192,1024] bf16 (aliases Ccat/Bcat, dead)
    u16*   Wmain    = (u16*)(ws + 48 * MB);       // [1024,1024] bf16
    u16*   Cwbf     = (u16*)(ws + 50 * MB);       // [1024,2048] bf16
    // hp_bf: big = fresh region above 54MB (partials stay live during casts);
    //        small = aliases partials+16MB region (reduce must finish first).
    u16*   hp_bf    = big ? (u16*)(ws + 54 * MB) : (u16*)(ws + 16 * MB);

    // 1) prep: Ccat=[Cr|-Ci] + Cwbf (fused, Cr/Ci read once); Bcat=[Br^T|Bi^T]
    prep_kernel<<<6144, 256, 0, stream>>>(Cr, Ci, Br, Bi, v_log, th_log,
                                          Ccat, Bcat, Cwbf);
    // 2) partials = Ccat @ Bcat^T (split-K=4, 256 blocks = 1/CU, no tail)
    gemm_splitk_kernel<<<dim3(8, 8, 4), 256, 0, stream>>>(Ccat, Bcat, partials);
    // 3) Wmain = bf16(sum partials); x/h_prev -> bf16
    if (big) {
        reduce_cast_kernel<<<25600, 256, 0, stream>>>(partials, x, h_prev,
                                                      Wmain, x_bf, hp_bf);
    } else {
        reduce_only_kernel<<<1024, 256, 0, stream>>>(partials, Wmain);
        cast_both_kernel<<<24576, 256, 0, stream>>>(x, h_prev, x_bf);
    }
    // 4) out = [x_bf | hp_bf] @ [Wmain | Cwbf]^T  (256x128 tile, 3-deep pipeline)
    gemm_main_kernel<<<256, 512, 0, stream>>>(x_bf, hp_bf, Wmain, Cwbf, out);
}

// Round 7
// 239.422 us; speedup vs baseline: 1.2155x; 1.0116x over previous
//
#include <hip/hip_runtime.h>
#include <stdint.h>

typedef unsigned short u16;
typedef short bf16x8 __attribute__((ext_vector_type(8)));   // 8 bf16 in 4 VGPRs
typedef float f32x4 __attribute__((ext_vector_type(4)));

typedef void as1_void __attribute__((address_space(1)));
typedef void as3_void __attribute__((address_space(3)));

__device__ inline u16 f32_to_bf16(float f) {
    uint32_t u = __builtin_bit_cast(uint32_t, f);
    u += 0x7fffu + ((u >> 16) & 1u);   // RNE (finite values only)
    return (u16)(u >> 16);
}

__device__ inline void gld_lds16(const void* g, void* l) {
    // async global->LDS, 16B/lane; HW dest = wave-uniform base + lane*16
    __builtin_amdgcn_global_load_lds((as1_void*)g, (as3_void*)l, 16, 0, 0);
}

// LDS tile layout (all GEMMs): R rows x 64 cols bf16, stored as R*8 chunks of
// 16B. Global (row, colchunk j) lives at chunk slot row*8 + (j ^ (row&7)).
// The XOR swizzle spreads same-column frag reads across all 32 banks (2-way max,
// free per m136) while keeping each staging issue 64 lane-contiguous slots.
// (Measured SQ_LDS_BANK_CONFLICT = 0 with this scheme.)

// ---------------- merged prep kernel ----------------
// blocks [0,2048):    read Cr,Ci once at (o,h); write Ccat[o][h]=bf16(Cr),
//                     Ccat[o][2048+h]=bf16(-Ci), Cwbf[o][h]=bf16(Cr*wr-Ci*wi)
//                     (w recomputed inline — same expressions as ever)
// blocks [2048,6144): Bcat[c][colOff+r] = bf16(src[r][c]) (32x32 LDS transpose)

__global__ void prep_kernel(const float* __restrict__ Cr, const float* __restrict__ Ci,
                            const float* __restrict__ Br, const float* __restrict__ Bi,
                            const float* __restrict__ v_log, const float* __restrict__ th_log,
                            u16* __restrict__ Ccat, u16* __restrict__ Bcat,
                            u16* __restrict__ Cwbf)
{
    __shared__ float t[32][33];
    const int b = blockIdx.x, tid = threadIdx.x;

    if (b < 2048) {
        // ---- fused: Ccat = [Cr | -Ci]  +  Cwbf = bf16(Cr*wr - Ci*wi) ----
        int i = b * 256 + tid;            // float4 index over [1024][2048]
        int e = i * 4;
        int o = e >> 11;
        int h = e & 2047;
        float4 cr = *(const float4*)(Cr + (size_t)o * 2048 + h);
        float4 ci = *(const float4*)(Ci + (size_t)o * 2048 + h);
        ushort4 ucr, uci, ucw;
        ucr.x = f32_to_bf16(cr.x); ucr.y = f32_to_bf16(cr.y);
        ucr.z = f32_to_bf16(cr.z); ucr.w = f32_to_bf16(cr.w);
        uci.x = f32_to_bf16(-ci.x); uci.y = f32_to_bf16(-ci.y);
        uci.z = f32_to_bf16(-ci.z); uci.w = f32_to_bf16(-ci.w);
        float4 vl = *(const float4*)(v_log + h);
        float4 tl = *(const float4*)(th_log + h);
        float mag, ang, wr, wi;
        mag = expf(-expf(vl.x)); ang = expf(tl.x); wr = mag * cosf(ang); wi = mag * sinf(ang);
        ucw.x = f32_to_bf16(cr.x * wr - ci.x * wi);
        mag = expf(-expf(vl.y)); ang = expf(tl.y); wr = mag * cosf(ang); wi = mag * sinf(ang);
        ucw.y = f32_to_bf16(cr.y * wr - ci.y * wi);
        mag = expf(-expf(vl.z)); ang = expf(tl.z); wr = mag * cosf(ang); wi = mag * sinf(ang);
        ucw.z = f32_to_bf16(cr.z * wr - ci.z * wi);
        mag = expf(-expf(vl.w)); ang = expf(tl.w); wr = mag * cosf(ang); wi = mag * sinf(ang);
        ucw.w = f32_to_bf16(cr.w * wr - ci.w * wi);
        *(ushort4*)(Ccat + (size_t)o * 4096 + h)        = ucr;
        *(ushort4*)(Ccat + (size_t)o * 4096 + 2048 + h) = uci;
        *(ushort4*)(Cwbf + (size_t)o * 2048 + h)        = ucw;
    } else {
        // ---- transpose-cast Bcat = [Br^T | Bi^T] ----
        int b2 = b - 2048;
        const float* src = (b2 & 2048) ? Bi : Br;
        int colOff = (b2 & 2048) ? 2048 : 0;
        int c0 = (b2 & 31) * 32, r0 = ((b2 >> 5) & 63) * 32;
        int tx = tid & 31, ty = tid >> 5;   // 32 x 8
#pragma unroll
        for (int j = 0; j < 4; j++)
            t[ty + j * 8][tx] = src[(size_t)(r0 + ty + j * 8) * 1024 + c0 + tx];
        __syncthreads();
#pragma unroll
        for (int j = 0; j < 4; j++)
            Bcat[(size_t)(c0 + ty + j * 8) * 4096 + colOff + r0 + tx] =
                f32_to_bf16(t[tx][ty + j * 8]);
    }
}

// ---------------- weight GEMM: split-K=4, 128x128 tile, 3-deep ring ----------------
// partials[bz][m][n] = sum_{k in 1024-chunk bz} Ccat[m][k] * Bcat[n][k], K=4096.
// Grid 8x8x4 = 256 blocks = 1/CU (4 waves = 1 wave/SIMD). The old 2-barrier
// lockstep paid the full vmcnt(0) drain per K-step with zero TLP (~1400
// cyc/K-step vs 512 MFMA floor). This is the gemm_main-proven 3-deep LDS ring:
// lookahead-2 staging, counted vmcnt(8) (8 issues/stage), raw s_barrier +
// compiler fences. MFMA/frag math, K order, partial layout all unchanged.
// NO in-kernel reduction tail (R1 lesson: per-block device fence = 4x slowdown).

__global__ __launch_bounds__(256)
void gemm_splitk_kernel(const u16* __restrict__ A, const u16* __restrict__ B,
                        float* __restrict__ partials)
{
    // per buffer: A = 128x64 bf16 (8192 u16), B = 128x64 (8192 u16) at offset 8192
    __shared__ __align__(16) u16 lds[3][16384];
    const int K = 4096;

    const int tid = threadIdx.x, wid = tid >> 6, lane = tid & 63;
    const int quad = lane >> 4, l16 = lane & 15;
    const int wm = wid >> 1, wn = wid & 1;
    const int bm = blockIdx.y, bn = blockIdx.x, bz = blockIdx.z;
    const int kb = bz * 1024;

    // staging slot geometry (per thread): 4 A issues + 4 B issues x 256 thr
    int sr[4], sj[4];
#pragma unroll
    for (int q = 0; q < 4; q++) {
        int s = q * 256 + tid;
        sr[q] = s >> 3;
        sj[q] = (s & 7) ^ (sr[q] & 7);
    }

    u16* buf0 = &lds[0][0];
    u16* buf1 = &lds[1][0];
    u16* buf2 = &lds[2][0];

    const f32x4 fz = {0.f, 0.f, 0.f, 0.f};
    f32x4 acc[4][4];
#pragma unroll
    for (int i = 0; i < 4; i++)
#pragma unroll
        for (int j = 0; j < 4; j++) acc[i][j] = fz;

    // stage K-tile t (0..15; k0 = kb + t*64) into buf: 4 A + 4 B issues
    auto stage = [&](int tt, u16* buf) {
        int koff = kb + tt * 64;
#pragma unroll
        for (int q = 0; q < 4; q++) {
            gld_lds16(A + (size_t)(bm * 128 + sr[q]) * K + koff + sj[q] * 8,
                      buf + (q * 256 + tid) * 8);
            gld_lds16(B + (size_t)(bn * 128 + sr[q]) * K + koff + sj[q] * 8,
                      buf + 8192 + (q * 256 + tid) * 8);
        }
    };

    // compute one K-tile (32 MFMA/wave, ks = 0,1) from buf — identical math
    auto compute = [&](const u16* buf) {
#pragma unroll
        for (int ks = 0; ks < 2; ks++) {
            bf16x8 af[4], bfr[4];
#pragma unroll
            for (int i = 0; i < 4; i++) {
                int r = wm * 64 + i * 16 + l16;
                af[i] = *(const bf16x8*)(buf + (r * 8 + ((ks * 4 + quad) ^ (r & 7))) * 8);
            }
#pragma unroll
            for (int j = 0; j < 4; j++) {
                int r = wn * 64 + j * 16 + l16;
                bfr[j] = *(const bf16x8*)(buf + 8192 + (r * 8 + ((ks * 4 + quad) ^ (r & 7))) * 8);
            }
            __builtin_amdgcn_s_setprio(1);
#pragma unroll
            for (int i = 0; i < 4; i++)
#pragma unroll
                for (int j = 0; j < 4; j++)
                    acc[i][j] = __builtin_amdgcn_mfma_f32_16x16x32_bf16(af[i], bfr[j], acc[i][j], 0, 0, 0);
            __builtin_amdgcn_s_setprio(0);
        }
    };

#define PUBLISH(N)                                          \
    asm volatile("s_waitcnt vmcnt(" #N ")" ::: "memory");   \
    __builtin_amdgcn_s_barrier();                           \
    asm volatile("" ::: "memory")

    // prologue: stage tiles 0,1; publish tile 0 (tile 1 still in flight)
    stage(0, buf0);
    stage(1, buf1);
    PUBLISH(8);

    // steady state: 4 triples, computing tiles 0..11, staging tiles 2..13
#pragma unroll 1
    for (int it = 0; it < 4; it++) {
        stage(3 * it + 2, buf2); compute(buf0); PUBLISH(8);
        stage(3 * it + 3, buf0); compute(buf1); PUBLISH(8);
        stage(3 * it + 4, buf1); compute(buf2); PUBLISH(8);
    }
    // tail: tiles 12 (buf0), 13 (buf1), 14 (buf2), 15 (buf0)
    stage(14, buf2); compute(buf0); PUBLISH(8);
    stage(15, buf0); compute(buf1); PUBLISH(8);
    compute(buf2); PUBLISH(0);
    compute(buf0);
#undef PUBLISH

    float* P = partials + ((size_t)bz << 20);
    const int gm = bm * 128 + wm * 64, gn = bn * 128 + wn * 64;
#pragma unroll
    for (int i = 0; i < 4; i++)
#pragma unroll
        for (int j = 0; j < 4; j++) {
            int col = gn + j * 16 + l16;
#pragma unroll
            for (int r = 0; r < 4; r++)
                P[(size_t)(gm + i * 16 + quad * 4 + r) * 1024 + col] = acc[i][j][r];
        }
}

// ---------------- reduce + cast (merged; big tier) ----------------
// blocks [0,1024):        Wmain = bf16(sum_z partials[z]) (z order 0..3)
// blocks [1024,9216):     x_bf  = bf16(x)
// blocks [9216,25600):    hp_bf = bf16(h_prev)
// Launches AFTER splitk (stream order = the fence); hp_bf does not alias partials.

__global__ void reduce_cast_kernel(const float* __restrict__ partials,
                                   const float* __restrict__ x,
                                   const float* __restrict__ h_prev,
                                   u16* __restrict__ Wmain,
                                   u16* __restrict__ x_bf,
                                   u16* __restrict__ hp_bf)
{
    const int b = blockIdx.x, tid = threadIdx.x;
    if (b < 1024) {
        int i = b * 256 + tid;
        int e = i * 4;
        float4 s = *(const float4*)(partials + e);
#pragma unroll
        for (int z = 1; z < 4; z++) {
            float4 p = *(const float4*)(partials + ((size_t)z << 20) + e);
            s.x += p.x; s.y += p.y; s.z += p.z; s.w += p.w;
        }
        ushort4 u;
        u.x = f32_to_bf16(s.x); u.y = f32_to_bf16(s.y);
        u.z = f32_to_bf16(s.z); u.w = f32_to_bf16(s.w);
        ((ushort4*)Wmain)[i] = u;
    } else if (b < 9216) {
        int i = (b - 1024) * 256 + tid;
        float4 f = ((const float4*)x)[i];
        ushort4 o;
        o.x = f32_to_bf16(f.x); o.y = f32_to_bf16(f.y);
        o.z = f32_to_bf16(f.z); o.w = f32_to_bf16(f.w);
        ((ushort4*)x_bf)[i] = o;
    } else {
        int i = (b - 9216) * 256 + tid;
        float4 f = ((const float4*)h_prev)[i];
        ushort4 o;
        o.x = f32_to_bf16(f.x); o.y = f32_to_bf16(f.y);
        o.z = f32_to_bf16(f.z); o.w = f32_to_bf16(f.w);
        ((ushort4*)hp_bf)[i] = o;
    }
}

// ---------------- small-workspace fallbacks ----------------

__global__ void reduce_only_kernel(const float* __restrict__ partials,
                                   u16* __restrict__ Wmain) {
    int i = blockIdx.x * blockDim.x + threadIdx.x;   // 1024 blocks x 256
    int e = i * 4;
    float4 s = *(const float4*)(partials + e);
#pragma unroll
    for (int z = 1; z < 4; z++) {
        float4 p = *(const float4*)(partials + ((size_t)z << 20) + e);
        s.x += p.x; s.y += p.y; s.z += p.z; s.w += p.w;
    }
    ushort4 u;
    u.x = f32_to_bf16(s.x); u.y = f32_to_bf16(s.y);
    u.z = f32_to_bf16(s.z); u.w = f32_to_bf16(s.w);
    ((ushort4*)Wmain)[i] = u;
}

// dst[0..16MB) = bf16(x), dst[16MB..48MB) = bf16(h_prev) (adjacent)
__global__ void cast_both_kernel(const float* __restrict__ x,
                                 const float* __restrict__ h_prev,
                                 u16* __restrict__ dst) {
    const int n4x = 8192 * 1024 / 4;     // 2097152
    int i = blockIdx.x * blockDim.x + threadIdx.x;
    float4 f = (i < n4x) ? ((const float4*)x)[i] : ((const float4*)h_prev)[i - n4x];
    ushort4 o;
    o.x = f32_to_bf16(f.x); o.y = f32_to_bf16(f.y);
    o.z = f32_to_bf16(f.z); o.w = f32_to_bf16(f.w);
    ((ushort4*)dst)[i] = o;
}

// ---------------- main GEMM (R3-proven: 256x128 tile, 3-deep ring) ----------------
// out[8192,1024] = [x_bf | hp_bf] @ [Wmain | Cwbf]^T, virtual K = 48 tiles of 64
// (tiles 0..15 from x@Wmain^T, 16..47 from hp@Cwbf^T — same accumulation order
// as all passing versions -> identical numerics).
// BM=256 BN=128 BK=64, 512 thr (8 waves, 4Mx2N, per-wave 64x64). 3-deep LDS ring
// (144 KB), lookahead-2 staging, counted vmcnt(6) (never drain 0 in loop),
// raw s_barrier + compiler fences, setprio around MFMA clusters. Grid = 256
// blocks = 1/CU; bm = id&31 so the 8 bn-sharers of an A-strip are co-XCD.
// DO NOT co-schedule BW work with this kernel (R4/R5 lessons: any added HBM
// latency lands on the per-tile drain and halves throughput).

__global__ __launch_bounds__(512)
void gemm_main_kernel(const u16* __restrict__ Axb, const u16* __restrict__ Ahb,
                      const u16* __restrict__ Bw,  const u16* __restrict__ Bcw,
                      float* __restrict__ out)
{
    // per buffer: A = 256x64 bf16 (16384 u16), B = 128x64 (8192 u16) at offset 16384
    __shared__ __align__(16) u16 lds[3][24576];

    const int tid = threadIdx.x, wid = tid >> 6, lane = tid & 63;
    const int quad = lane >> 4, l16 = lane & 15;
    const int wm = wid >> 1, wn = wid & 1;          // 4 M-waves x 2 N-waves
    const int id = blockIdx.x;
    const int bm = id & 31, bn = id >> 5;

    // staging slot geometry (per thread): A = 4 issues x 512 thr, B = 2 issues
    int srA[4], sjA[4], srB[2], sjB[2];
#pragma unroll
    for (int q = 0; q < 4; q++) {
        int s = q * 512 + tid;
        srA[q] = s >> 3;
        sjA[q] = (s & 7) ^ (srA[q] & 7);
    }
#pragma unroll
    for (int q = 0; q < 2; q++) {
        int s = q * 512 + tid;
        srB[q] = s >> 3;
        sjB[q] = (s & 7) ^ (srB[q] & 7);
    }

    u16* buf0 = &lds[0][0];
    u16* buf1 = &lds[1][0];
    u16* buf2 = &lds[2][0];

    const f32x4 fz = {0.f, 0.f, 0.f, 0.f};
    f32x4 acc[4][4];
#pragma unroll
    for (int i = 0; i < 4; i++)
#pragma unroll
        for (int j = 0; j < 4; j++) acc[i][j] = fz;

    // stage K-tile tt (0..47) into buf: 6 gld_lds per thread (4 A + 2 B)
    auto stage = [&](int tt, u16* buf) {
        const u16* Ab; const u16* Bb; int KS, koff;
        if (tt < 16) { Ab = Axb; Bb = Bw;  KS = 1024; koff = tt * 64; }
        else         { Ab = Ahb; Bb = Bcw; KS = 2048; koff = (tt - 16) * 64; }
#pragma unroll
        for (int q = 0; q < 4; q++)
            gld_lds16(Ab + (size_t)(bm * 256 + srA[q]) * KS + koff + sjA[q] * 8,
                      buf + (q * 512 + tid) * 8);
#pragma unroll
        for (int q = 0; q < 2; q++)
            gld_lds16(Bb + (size_t)(bn * 128 + srB[q]) * KS + koff + sjB[q] * 8,
                      buf + 16384 + (q * 512 + tid) * 8);
    };

    // compute one K-tile (32 MFMA/wave, ks = 0,1) from buf
    auto compute = [&](const u16* buf) {
#pragma unroll
        for (int ks = 0; ks < 2; ks++) {
            bf16x8 af[4], bfr[4];
#pragma unroll
            for (int i = 0; i < 4; i++) {
                int r = wm * 64 + i * 16 + l16;
                af[i] = *(const bf16x8*)(buf + (r * 8 + ((ks * 4 + quad) ^ (r & 7))) * 8);
            }
#pragma unroll
            for (int j = 0; j < 4; j++) {
                int r = wn * 64 + j * 16 + l16;
                bfr[j] = *(const bf16x8*)(buf + 16384 + (r * 8 + ((ks * 4 + quad) ^ (r & 7))) * 8);
            }
            __builtin_amdgcn_s_setprio(1);
#pragma unroll
            for (int i = 0; i < 4; i++)
#pragma unroll
                for (int j = 0; j < 4; j++)
                    acc[i][j] = __builtin_amdgcn_mfma_f32_16x16x32_bf16(af[i], bfr[j], acc[i][j], 0, 0, 0);
            __builtin_amdgcn_s_setprio(0);
        }
    };

#define PUBLISH(N)                                          \
    asm volatile("s_waitcnt vmcnt(" #N ")" ::: "memory");   \
    __builtin_amdgcn_s_barrier();                           \
    asm volatile("" ::: "memory")

    // prologue: stage tiles 0,1; publish tile 0 (tile 1 still in flight)
    stage(0, buf0);
    stage(1, buf1);
    PUBLISH(6);

    // steady state: 15 triples, tiles 0..44; stage lookahead-2 (tiles 2..46)
#pragma unroll 1
    for (int it = 0; it < 15; it++) {
        stage(3 * it + 2, buf2); compute(buf0); PUBLISH(6);
        stage(3 * it + 3, buf0); compute(buf1); PUBLISH(6);
        stage(3 * it + 4, buf1); compute(buf2); PUBLISH(6);
    }
    // tail: tiles 45 (buf0), 46 (buf1), 47 (buf2)
    stage(47, buf2); compute(buf0); PUBLISH(6);
    compute(buf1); PUBLISH(0);
    compute(buf2);
#undef PUBLISH

    const int gm = bm * 256 + wm * 64, gn = bn * 128 + wn * 64;
#pragma unroll
    for (int i = 0; i < 4; i++)
#pragma unroll
        for (int j = 0; j < 4; j++) {
            int col = gn + j * 16 + l16;
#pragma unroll
            for (int r = 0; r < 4; r++)
                out[(size_t)(gm + i * 16 + quad * 4 + r) * 1024 + col] = acc[i][j][r];
        }
}

// ---------------- launch ----------------

extern "C" void kernel_launch(void* const* d_in, const int* in_sizes, int n_in,
                              void* d_out, int out_size, void* d_ws, size_t ws_size,
                              hipStream_t stream)
{
    const float* x      = (const float*)d_in[0];
    const float* h_prev = (const float*)d_in[1];
    const float* Br     = (const float*)d_in[2];
    const float* Bi     = (const float*)d_in[3];
    const float* Cr     = (const float*)d_in[4];
    const float* Ci     = (const float*)d_in[5];
    const float* v_log  = (const float*)d_in[6];
    const float* th_log = (const float*)d_in[7];
    float* out = (float*)d_out;

    const size_t MB = 1024 * 1024;
    if (ws_size < 54 * MB) return;
    const bool big = (ws_size >= 86 * MB);   // non-aliased hp_bf -> merged reduce+cast

    char* ws = (char*)d_ws;
    u16*   Ccat     = (u16*)ws;                   // [1024,4096] bf16
    u16*   Bcat     = (u16*)(ws + 8 * MB);        // [1024,4096] bf16 = [BrT|BiT]
    float* partials = (float*)(ws + 16 * MB);     // [4][1024][1024] f32 (split-K=4)
    u16*   x_bf     = (u16*)ws;                   // [8192,1024] bf16 (aliases Ccat/Bcat, dead)
    u16*   Wmain    = (u16*)(ws + 48 * MB);       // [1024,1024] bf16
    u16*   Cwbf     = (u16*)(ws + 50 * MB);       // [1024,2048] bf16
    // hp_bf: big = fresh region above 54MB (partials stay live during casts);
    //        small = aliases partials+16MB region (reduce must finish first).
    u16*   hp_bf    = big ? (u16*)(ws + 54 * MB) : (u16*)(ws + 16 * MB);

    // 1) prep: Ccat=[Cr|-Ci] + Cwbf (fused, Cr/Ci read once); Bcat=[Br^T|Bi^T]
    prep_kernel<<<6144, 256, 0, stream>>>(Cr, Ci, Br, Bi, v_log, th_log,
                                          Ccat, Bcat, Cwbf);
    // 2) partials = Ccat @ Bcat^T (split-K=4, 256 blocks = 1/CU, 3-deep ring)
    gemm_splitk_kernel<<<dim3(8, 8, 4), 256, 0, stream>>>(Ccat, Bcat, partials);
    // 3) Wmain = bf16(sum partials); x/h_prev -> bf16
    if (big) {
        reduce_cast_kernel<<<25600, 256, 0, stream>>>(partials, x, h_prev,
                                                      Wmain, x_bf, hp_bf);
    } else {
        reduce_only_kernel<<<1024, 256, 0, stream>>>(partials, Wmain);
        cast_both_kernel<<<24576, 256, 0, stream>>>(x, h_prev, x_bf);
    }
    // 4) out = [x_bf | hp_bf] @ [Wmain | Cwbf]^T  (256x128 tile, 3-deep pipeline)
    gemm_main_kernel<<<256, 512, 0, stream>>>(x_bf, hp_bf, Wmain, Cwbf, out);
}

// Round 8
// 237.192 us; speedup vs baseline: 1.2269x; 1.0094x over previous
//
#include <hip/hip_runtime.h>
#include <stdint.h>

typedef unsigned short u16;
typedef short bf16x8 __attribute__((ext_vector_type(8)));   // 8 bf16 in 4 VGPRs
typedef float f32x4 __attribute__((ext_vector_type(4)));

typedef void as1_void __attribute__((address_space(1)));
typedef void as3_void __attribute__((address_space(3)));

__device__ inline u16 f32_to_bf16(float f) {
    uint32_t u = __builtin_bit_cast(uint32_t, f);
    u += 0x7fffu + ((u >> 16) & 1u);   // RNE (finite values only)
    return (u16)(u >> 16);
}

__device__ inline void gld_lds16(const void* g, void* l) {
    // async global->LDS, 16B/lane; HW dest = wave-uniform base + lane*16
    __builtin_amdgcn_global_load_lds((as1_void*)g, (as3_void*)l, 16, 0, 0);
}

// LDS tile layout (all GEMMs): R rows x 64 cols bf16, stored as R*8 chunks of
// 16B. Global (row, colchunk j) lives at chunk slot row*8 + (j ^ (row&7)).
// The XOR swizzle spreads same-column frag reads across all 32 banks (2-way max,
// free per m136) while keeping each staging issue 64 lane-contiguous slots.
// (Measured SQ_LDS_BANK_CONFLICT = 0 with this scheme.)

// ---------------- merged prep (+cast) kernel ----------------
// blocks [0,2048):       read Cr,Ci once at (o,h); write Ccat[o][h]=bf16(Cr),
//                        Ccat[o][2048+h]=bf16(-Ci), Cwbf[o][h]=bf16(Cr*wr-Ci*wi)
// blocks [2048,6144):    Bcat[c][colOff+r] = bf16(src[r][c]) (32x32 LDS transpose)
// blocks [6144,14336):   x_bf  = bf16(x)        (big tier only — grid 30720)
// blocks [14336,30720):  hp_bf = bf16(h_prev)   (big tier only)
// The casts have NO dependency on any prep output; co-scheduling BW-streaming
// with BW-streaming is safe (R5's failure was BW work next to a latency-
// sensitive lockstep GEMM — not this).

__global__ void prep_kernel(const float* __restrict__ Cr, const float* __restrict__ Ci,
                            const float* __restrict__ Br, const float* __restrict__ Bi,
                            const float* __restrict__ v_log, const float* __restrict__ th_log,
                            const float* __restrict__ x, const float* __restrict__ h_prev,
                            u16* __restrict__ Ccat, u16* __restrict__ Bcat,
                            u16* __restrict__ Cwbf,
                            u16* __restrict__ x_bf, u16* __restrict__ hp_bf)
{
    __shared__ float t[32][33];
    const int b = blockIdx.x, tid = threadIdx.x;

    if (b < 2048) {
        // ---- fused: Ccat = [Cr | -Ci]  +  Cwbf = bf16(Cr*wr - Ci*wi) ----
        int i = b * 256 + tid;            // float4 index over [1024][2048]
        int e = i * 4;
        int o = e >> 11;
        int h = e & 2047;
        float4 cr = *(const float4*)(Cr + (size_t)o * 2048 + h);
        float4 ci = *(const float4*)(Ci + (size_t)o * 2048 + h);
        ushort4 ucr, uci, ucw;
        ucr.x = f32_to_bf16(cr.x); ucr.y = f32_to_bf16(cr.y);
        ucr.z = f32_to_bf16(cr.z); ucr.w = f32_to_bf16(cr.w);
        uci.x = f32_to_bf16(-ci.x); uci.y = f32_to_bf16(-ci.y);
        uci.z = f32_to_bf16(-ci.z); uci.w = f32_to_bf16(-ci.w);
        float4 vl = *(const float4*)(v_log + h);
        float4 tl = *(const float4*)(th_log + h);
        float mag, ang, wr, wi;
        mag = expf(-expf(vl.x)); ang = expf(tl.x); wr = mag * cosf(ang); wi = mag * sinf(ang);
        ucw.x = f32_to_bf16(cr.x * wr - ci.x * wi);
        mag = expf(-expf(vl.y)); ang = expf(tl.y); wr = mag * cosf(ang); wi = mag * sinf(ang);
        ucw.y = f32_to_bf16(cr.y * wr - ci.y * wi);
        mag = expf(-expf(vl.z)); ang = expf(tl.z); wr = mag * cosf(ang); wi = mag * sinf(ang);
        ucw.z = f32_to_bf16(cr.z * wr - ci.z * wi);
        mag = expf(-expf(vl.w)); ang = expf(tl.w); wr = mag * cosf(ang); wi = mag * sinf(ang);
        ucw.w = f32_to_bf16(cr.w * wr - ci.w * wi);
        *(ushort4*)(Ccat + (size_t)o * 4096 + h)        = ucr;
        *(ushort4*)(Ccat + (size_t)o * 4096 + 2048 + h) = uci;
        *(ushort4*)(Cwbf + (size_t)o * 2048 + h)        = ucw;
    } else if (b < 6144) {
        // ---- transpose-cast Bcat = [Br^T | Bi^T] ----
        int b2 = b - 2048;
        const float* src = (b2 & 2048) ? Bi : Br;
        int colOff = (b2 & 2048) ? 2048 : 0;
        int c0 = (b2 & 31) * 32, r0 = ((b2 >> 5) & 63) * 32;
        int tx = tid & 31, ty = tid >> 5;   // 32 x 8
#pragma unroll
        for (int j = 0; j < 4; j++)
            t[ty + j * 8][tx] = src[(size_t)(r0 + ty + j * 8) * 1024 + c0 + tx];
        __syncthreads();
#pragma unroll
        for (int j = 0; j < 4; j++)
            Bcat[(size_t)(c0 + ty + j * 8) * 4096 + colOff + r0 + tx] =
                f32_to_bf16(t[tx][ty + j * 8]);
    } else if (b < 14336) {
        // ---- x_bf = bf16(x) ----
        int i = (b - 6144) * 256 + tid;
        float4 f = ((const float4*)x)[i];
        ushort4 o;
        o.x = f32_to_bf16(f.x); o.y = f32_to_bf16(f.y);
        o.z = f32_to_bf16(f.z); o.w = f32_to_bf16(f.w);
        ((ushort4*)x_bf)[i] = o;
    } else {
        // ---- hp_bf = bf16(h_prev) ----
        int i = (b - 14336) * 256 + tid;
        float4 f = ((const float4*)h_prev)[i];
        ushort4 o;
        o.x = f32_to_bf16(f.x); o.y = f32_to_bf16(f.y);
        o.z = f32_to_bf16(f.z); o.w = f32_to_bf16(f.w);
        ((ushort4*)hp_bf)[i] = o;
    }
}

// ---------------- weight GEMM: split-K=4, 128x128 tile, 3-deep ring ----------------
// partials[bz][m][n] = sum_{k in 1024-chunk bz} Ccat[m][k] * Bcat[n][k], K=4096.
// Grid 8x8x4 = 256 blocks = 1/CU. gemm_main-proven 3-deep LDS ring: lookahead-2
// staging, counted vmcnt(8), raw s_barrier + compiler fences. NO in-kernel
// reduction tail (R1 lesson: per-block device fence = 4x slowdown).

__global__ __launch_bounds__(256)
void gemm_splitk_kernel(const u16* __restrict__ A, const u16* __restrict__ B,
                        float* __restrict__ partials)
{
    // per buffer: A = 128x64 bf16 (8192 u16), B = 128x64 (8192 u16) at offset 8192
    __shared__ __align__(16) u16 lds[3][16384];
    const int K = 4096;

    const int tid = threadIdx.x, wid = tid >> 6, lane = tid & 63;
    const int quad = lane >> 4, l16 = lane & 15;
    const int wm = wid >> 1, wn = wid & 1;
    const int bm = blockIdx.y, bn = blockIdx.x, bz = blockIdx.z;
    const int kb = bz * 1024;

    // staging slot geometry (per thread): 4 A issues + 4 B issues x 256 thr
    int sr[4], sj[4];
#pragma unroll
    for (int q = 0; q < 4; q++) {
        int s = q * 256 + tid;
        sr[q] = s >> 3;
        sj[q] = (s & 7) ^ (sr[q] & 7);
    }

    u16* buf0 = &lds[0][0];
    u16* buf1 = &lds[1][0];
    u16* buf2 = &lds[2][0];

    const f32x4 fz = {0.f, 0.f, 0.f, 0.f};
    f32x4 acc[4][4];
#pragma unroll
    for (int i = 0; i < 4; i++)
#pragma unroll
        for (int j = 0; j < 4; j++) acc[i][j] = fz;

    // stage K-tile t (0..15; k0 = kb + t*64) into buf: 4 A + 4 B issues
    auto stage = [&](int tt, u16* buf) {
        int koff = kb + tt * 64;
#pragma unroll
        for (int q = 0; q < 4; q++) {
            gld_lds16(A + (size_t)(bm * 128 + sr[q]) * K + koff + sj[q] * 8,
                      buf + (q * 256 + tid) * 8);
            gld_lds16(B + (size_t)(bn * 128 + sr[q]) * K + koff + sj[q] * 8,
                      buf + 8192 + (q * 256 + tid) * 8);
        }
    };

    // compute one K-tile (32 MFMA/wave, ks = 0,1) from buf — identical math
    auto compute = [&](const u16* buf) {
#pragma unroll
        for (int ks = 0; ks < 2; ks++) {
            bf16x8 af[4], bfr[4];
#pragma unroll
            for (int i = 0; i < 4; i++) {
                int r = wm * 64 + i * 16 + l16;
                af[i] = *(const bf16x8*)(buf + (r * 8 + ((ks * 4 + quad) ^ (r & 7))) * 8);
            }
#pragma unroll
            for (int j = 0; j < 4; j++) {
                int r = wn * 64 + j * 16 + l16;
                bfr[j] = *(const bf16x8*)(buf + 8192 + (r * 8 + ((ks * 4 + quad) ^ (r & 7))) * 8);
            }
            __builtin_amdgcn_s_setprio(1);
#pragma unroll
            for (int i = 0; i < 4; i++)
#pragma unroll
                for (int j = 0; j < 4; j++)
                    acc[i][j] = __builtin_amdgcn_mfma_f32_16x16x32_bf16(af[i], bfr[j], acc[i][j], 0, 0, 0);
            __builtin_amdgcn_s_setprio(0);
        }
    };

#define PUBLISH(N)                                          \
    asm volatile("s_waitcnt vmcnt(" #N ")" ::: "memory");   \
    __builtin_amdgcn_s_barrier();                           \
    asm volatile("" ::: "memory")

    // prologue: stage tiles 0,1; publish tile 0 (tile 1 still in flight)
    stage(0, buf0);
    stage(1, buf1);
    PUBLISH(8);

    // steady state: 4 triples, computing tiles 0..11, staging tiles 2..13
#pragma unroll 1
    for (int it = 0; it < 4; it++) {
        stage(3 * it + 2, buf2); compute(buf0); PUBLISH(8);
        stage(3 * it + 3, buf0); compute(buf1); PUBLISH(8);
        stage(3 * it + 4, buf1); compute(buf2); PUBLISH(8);
    }
    // tail: tiles 12 (buf0), 13 (buf1), 14 (buf2), 15 (buf0)
    stage(14, buf2); compute(buf0); PUBLISH(8);
    stage(15, buf0); compute(buf1); PUBLISH(8);
    compute(buf2); PUBLISH(0);
    compute(buf0);
#undef PUBLISH

    float* P = partials + ((size_t)bz << 20);
    const int gm = bm * 128 + wm * 64, gn = bn * 128 + wn * 64;
#pragma unroll
    for (int i = 0; i < 4; i++)
#pragma unroll
        for (int j = 0; j < 4; j++) {
            int col = gn + j * 16 + l16;
#pragma unroll
            for (int r = 0; r < 4; r++)
                P[(size_t)(gm + i * 16 + quad * 4 + r) * 1024 + col] = acc[i][j][r];
        }
}

// ---------------- reduce: Wmain = bf16(sum_z partials[z]) ----------------
// z order 0..3 — same rounding as previous passing versions.

__global__ void reduce_only_kernel(const float* __restrict__ partials,
                                   u16* __restrict__ Wmain) {
    int i = blockIdx.x * blockDim.x + threadIdx.x;   // 1024 blocks x 256
    int e = i * 4;
    float4 s = *(const float4*)(partials + e);
#pragma unroll
    for (int z = 1; z < 4; z++) {
        float4 p = *(const float4*)(partials + ((size_t)z << 20) + e);
        s.x += p.x; s.y += p.y; s.z += p.z; s.w += p.w;
    }
    ushort4 u;
    u.x = f32_to_bf16(s.x); u.y = f32_to_bf16(s.y);
    u.z = f32_to_bf16(s.z); u.w = f32_to_bf16(s.w);
    ((ushort4*)Wmain)[i] = u;
}

// small-ws fallback: dst[0..16MB) = bf16(x), dst[16MB..48MB) = bf16(h_prev)
__global__ void cast_both_kernel(const float* __restrict__ x,
                                 const float* __restrict__ h_prev,
                                 u16* __restrict__ dst) {
    const int n4x = 8192 * 1024 / 4;     // 2097152
    int i = blockIdx.x * blockDim.x + threadIdx.x;
    float4 f = (i < n4x) ? ((const float4*)x)[i] : ((const float4*)h_prev)[i - n4x];
    ushort4 o;
    o.x = f32_to_bf16(f.x); o.y = f32_to_bf16(f.y);
    o.z = f32_to_bf16(f.z); o.w = f32_to_bf16(f.w);
    ((ushort4*)dst)[i] = o;
}

// ---------------- main GEMM (R3-proven: 256x128 tile, 3-deep ring) ----------------
// out[8192,1024] = [x_bf | hp_bf] @ [Wmain | Cwbf]^T, virtual K = 48 tiles of 64
// (tiles 0..15 from x@Wmain^T, 16..47 from hp@Cwbf^T — same accumulation order
// as all passing versions -> identical numerics).
// BM=256 BN=128 BK=64, 512 thr (8 waves, 4Mx2N, per-wave 64x64). 3-deep LDS ring
// (144 KB), lookahead-2 staging, counted vmcnt(6) (never drain 0 in loop),
// raw s_barrier + compiler fences, setprio around MFMA clusters. Grid = 256
// blocks = 1/CU; bm = id&31 so the 8 bn-sharers of an A-strip are co-XCD.
// DO NOT co-schedule BW work with this kernel (R4/R5 lessons: any added HBM
// latency lands on the per-tile drain and halves throughput).

__global__ __launch_bounds__(512)
void gemm_main_kernel(const u16* __restrict__ Axb, const u16* __restrict__ Ahb,
                      const u16* __restrict__ Bw,  const u16* __restrict__ Bcw,
                      float* __restrict__ out)
{
    // per buffer: A = 256x64 bf16 (16384 u16), B = 128x64 (8192 u16) at offset 16384
    __shared__ __align__(16) u16 lds[3][24576];

    const int tid = threadIdx.x, wid = tid >> 6, lane = tid & 63;
    const int quad = lane >> 4, l16 = lane & 15;
    const int wm = wid >> 1, wn = wid & 1;          // 4 M-waves x 2 N-waves
    const int id = blockIdx.x;
    const int bm = id & 31, bn = id >> 5;

    // staging slot geometry (per thread): A = 4 issues x 512 thr, B = 2 issues
    int srA[4], sjA[4], srB[2], sjB[2];
#pragma unroll
    for (int q = 0; q < 4; q++) {
        int s = q * 512 + tid;
        srA[q] = s >> 3;
        sjA[q] = (s & 7) ^ (srA[q] & 7);
    }
#pragma unroll
    for (int q = 0; q < 2; q++) {
        int s = q * 512 + tid;
        srB[q] = s >> 3;
        sjB[q] = (s & 7) ^ (srB[q] & 7);
    }

    u16* buf0 = &lds[0][0];
    u16* buf1 = &lds[1][0];
    u16* buf2 = &lds[2][0];

    const f32x4 fz = {0.f, 0.f, 0.f, 0.f};
    f32x4 acc[4][4];
#pragma unroll
    for (int i = 0; i < 4; i++)
#pragma unroll
        for (int j = 0; j < 4; j++) acc[i][j] = fz;

    // stage K-tile tt (0..47) into buf: 6 gld_lds per thread (4 A + 2 B)
    auto stage = [&](int tt, u16* buf) {
        const u16* Ab; const u16* Bb; int KS, koff;
        if (tt < 16) { Ab = Axb; Bb = Bw;  KS = 1024; koff = tt * 64; }
        else         { Ab = Ahb; Bb = Bcw; KS = 2048; koff = (tt - 16) * 64; }
#pragma unroll
        for (int q = 0; q < 4; q++)
            gld_lds16(Ab + (size_t)(bm * 256 + srA[q]) * KS + koff + sjA[q] * 8,
                      buf + (q * 512 + tid) * 8);
#pragma unroll
        for (int q = 0; q < 2; q++)
            gld_lds16(Bb + (size_t)(bn * 128 + srB[q]) * KS + koff + sjB[q] * 8,
                      buf + 16384 + (q * 512 + tid) * 8);
    };

    // compute one K-tile (32 MFMA/wave, ks = 0,1) from buf
    auto compute = [&](const u16* buf) {
#pragma unroll
        for (int ks = 0; ks < 2; ks++) {
            bf16x8 af[4], bfr[4];
#pragma unroll
            for (int i = 0; i < 4; i++) {
                int r = wm * 64 + i * 16 + l16;
                af[i] = *(const bf16x8*)(buf + (r * 8 + ((ks * 4 + quad) ^ (r & 7))) * 8);
            }
#pragma unroll
            for (int j = 0; j < 4; j++) {
                int r = wn * 64 + j * 16 + l16;
                bfr[j] = *(const bf16x8*)(buf + 16384 + (r * 8 + ((ks * 4 + quad) ^ (r & 7))) * 8);
            }
            __builtin_amdgcn_s_setprio(1);
#pragma unroll
            for (int i = 0; i < 4; i++)
#pragma unroll
                for (int j = 0; j < 4; j++)
                    acc[i][j] = __builtin_amdgcn_mfma_f32_16x16x32_bf16(af[i], bfr[j], acc[i][j], 0, 0, 0);
            __builtin_amdgcn_s_setprio(0);
        }
    };

#define PUBLISH(N)                                          \
    asm volatile("s_waitcnt vmcnt(" #N ")" ::: "memory");   \
    __builtin_amdgcn_s_barrier();                           \
    asm volatile("" ::: "memory")

    // prologue: stage tiles 0,1; publish tile 0 (tile 1 still in flight)
    stage(0, buf0);
    stage(1, buf1);
    PUBLISH(6);

    // steady state: 15 triples, tiles 0..44; stage lookahead-2 (tiles 2..46)
#pragma unroll 1
    for (int it = 0; it < 15; it++) {
        stage(3 * it + 2, buf2); compute(buf0); PUBLISH(6);
        stage(3 * it + 3, buf0); compute(buf1); PUBLISH(6);
        stage(3 * it + 4, buf1); compute(buf2); PUBLISH(6);
    }
    // tail: tiles 45 (buf0), 46 (buf1), 47 (buf2)
    stage(47, buf2); compute(buf0); PUBLISH(6);
    compute(buf1); PUBLISH(0);
    compute(buf2);
#undef PUBLISH

    const int gm = bm * 256 + wm * 64, gn = bn * 128 + wn * 64;
#pragma unroll
    for (int i = 0; i < 4; i++)
#pragma unroll
        for (int j = 0; j < 4; j++) {
            int col = gn + j * 16 + l16;
#pragma unroll
            for (int r = 0; r < 4; r++)
                out[(size_t)(gm + i * 16 + quad * 4 + r) * 1024 + col] = acc[i][j][r];
        }
}

// ---------------- launch ----------------

extern "C" void kernel_launch(void* const* d_in, const int* in_sizes, int n_in,
                              void* d_out, int out_size, void* d_ws, size_t ws_size,
                              hipStream_t stream)
{
    const float* x      = (const float*)d_in[0];
    const float* h_prev = (const float*)d_in[1];
    const float* Br     = (const float*)d_in[2];
    const float* Bi     = (const float*)d_in[3];
    const float* Cr     = (const float*)d_in[4];
    const float* Ci     = (const float*)d_in[5];
    const float* v_log  = (const float*)d_in[6];
    const float* th_log = (const float*)d_in[7];
    float* out = (float*)d_out;

    const size_t MB = 1024 * 1024;
    if (ws_size < 54 * MB) return;
    const bool big = (ws_size >= 86 * MB);   // fully-disjoint layout -> cast in prep

    char* ws = (char*)d_ws;
    u16*   Ccat     = (u16*)ws;                   // [1024,4096] bf16
    u16*   Bcat     = (u16*)(ws + 8 * MB);        // [1024,4096] bf16 = [BrT|BiT]
    float* partials = (float*)(ws + 16 * MB);     // [4][1024][1024] f32 (split-K=4)
    u16*   Wmain    = (u16*)(ws + 48 * MB);       // [1024,1024] bf16
    u16*   Cwbf     = (u16*)(ws + 50 * MB);       // [1024,2048] bf16
    // big: x_bf @32MB (disjoint from everything live), hp_bf @54MB.
    // small: x_bf aliases Ccat/Bcat (cast runs after splitk), hp_bf over partials.
    u16*   x_bf     = big ? (u16*)(ws + 32 * MB) : (u16*)ws;
    u16*   hp_bf    = big ? (u16*)(ws + 54 * MB) : (u16*)(ws + 16 * MB);

    if (big) {
        // 1) prep + casts (all BW-streaming, no inter-dependency)
        prep_kernel<<<30720, 256, 0, stream>>>(Cr, Ci, Br, Bi, v_log, th_log,
                                               x, h_prev,
                                               Ccat, Bcat, Cwbf, x_bf, hp_bf);
        // 2) partials = Ccat @ Bcat^T (split-K=4, 256 blocks = 1/CU, 3-deep ring)
        gemm_splitk_kernel<<<dim3(8, 8, 4), 256, 0, stream>>>(Ccat, Bcat, partials);
        // 3) Wmain = bf16(sum partials)
        reduce_only_kernel<<<1024, 256, 0, stream>>>(partials, Wmain);
    } else {
        prep_kernel<<<6144, 256, 0, stream>>>(Cr, Ci, Br, Bi, v_log, th_log,
                                              x, h_prev,
                                              Ccat, Bcat, Cwbf, x_bf, hp_bf);
        gemm_splitk_kernel<<<dim3(8, 8, 4), 256, 0, stream>>>(Ccat, Bcat, partials);
        reduce_only_kernel<<<1024, 256, 0, stream>>>(partials, Wmain);
        cast_both_kernel<<<24576, 256, 0, stream>>>(x, h_prev, x_bf);
    }
    // 4) out = [x_bf | hp_bf] @ [Wmain | Cwbf]^T  (256x128 tile, 3-deep pipeline)
    gemm_main_kernel<<<256, 512, 0, stream>>>(x_bf, hp_bf, Wmain, Cwbf, out);
}